// Round 10
// baseline (374.352 us; speedup 1.0000x reference)
//
#include <hip/hip_runtime.h>
#include <cmath>

#define TT 1024
#define HH 8
#define KVHN 4

typedef unsigned short u16;
typedef __attribute__((ext_vector_type(8))) short bf16x8;
typedef __attribute__((ext_vector_type(4))) float f32x4;

#define MFMA(a, b, c) __builtin_amdgcn_mfma_f32_16x16x32_bf16(a, b, c, 0, 0, 0)

__device__ __forceinline__ float bflo(unsigned u) { return __uint_as_float(u << 16); }
__device__ __forceinline__ float bfhi(unsigned u) { return __uint_as_float(u & 0xffff0000u); }
__device__ __forceinline__ u16 bfr(float f) {
  unsigned u = __float_as_uint(f);
  return (u16)((u + 0x7fffu + ((u >> 16) & 1u)) >> 16);
}

__device__ __forceinline__ bf16x8 ld8_g(const u16* __restrict__ p) {
  uint4 v = *reinterpret_cast<const uint4*>(p);
  return __builtin_bit_cast(bf16x8, v);
}
__device__ __forceinline__ bf16x8 ld8_lds(const u16* s, int col, int k8) {
  const uint4* p = reinterpret_cast<const uint4*>(s);
  return __builtin_bit_cast(bf16x8, p[col * 8 + (k8 ^ (col & 7))]);
}
// split v (4 consecutive rows r0..r0+3, r0%8 in {0,4}) into hi/lo bf16, store packed
__device__ __forceinline__ void st_split_lds(u16* sh, u16* sl, int col, int r0,
                                             f32x4 v) {
  u16 hh[4], ll[4];
#pragma unroll
  for (int j = 0; j < 4; ++j) {
    u16 hb = bfr(v[j]);
    hh[j] = hb;
    ll[j] = bfr(v[j] - __uint_as_float((unsigned)hb << 16));
  }
  uint2 ph, pl;
  ph.x = (unsigned)hh[0] | ((unsigned)hh[1] << 16);
  ph.y = (unsigned)hh[2] | ((unsigned)hh[3] << 16);
  pl.x = (unsigned)ll[0] | ((unsigned)ll[1] << 16);
  pl.y = (unsigned)ll[2] | ((unsigned)ll[3] << 16);
  int idx = col * 64 + (((r0 >> 3) ^ (col & 7)) << 3) + (r0 & 7);
  *reinterpret_cast<uint2*>(sh + idx) = ph;
  *reinterpret_cast<uint2*>(sl + idx) = pl;
}
__device__ __forceinline__ void st_split_g(u16* __restrict__ gh,
                                           u16* __restrict__ gl, size_t colbase,
                                           int r0, f32x4 v) {
  u16 hh[4], ll[4];
#pragma unroll
  for (int j = 0; j < 4; ++j) {
    u16 hb = bfr(v[j]);
    hh[j] = hb;
    ll[j] = bfr(v[j] - __uint_as_float((unsigned)hb << 16));
  }
  uint2 ph, pl;
  ph.x = (unsigned)hh[0] | ((unsigned)hh[1] << 16);
  ph.y = (unsigned)hh[2] | ((unsigned)hh[3] << 16);
  pl.x = (unsigned)ll[0] | ((unsigned)ll[1] << 16);
  pl.y = (unsigned)ll[2] | ((unsigned)ll[3] << 16);
  size_t idx = colbase + (size_t)(r0 & ~7) + (r0 & 7);
  *reinterpret_cast<uint2*>(gh + idx) = ph;
  *reinterpret_cast<uint2*>(gl + idx) = pl;
}

// ---------------------------------------------------------------------------
// K1: QKV projection as tiled GEMM + fused RoPE. (unchanged, proven)
// ---------------------------------------------------------------------------
__global__ __launch_bounds__(256) void qkv_kernel(
    const float* __restrict__ x, const float* __restrict__ cosb,
    const float* __restrict__ sinb, const float* __restrict__ Wq,
    const float* __restrict__ Wk, const float* __restrict__ Wv,
    float* __restrict__ Q, float* __restrict__ Kt, float* __restrict__ Vt) {
  const int bx = blockIdx.x, cy = blockIdx.y;
  const int tid = threadIdx.x;
  const int ti = tid >> 4, tj = tid & 15;
  const int m0 = bx * 64;

  __shared__ float Xs[64][68];
  __shared__ float Ws[64][68];

  const float* Wsel;
  int wstride, wc0;
  if (cy < 8) { Wsel = Wq; wstride = 512; wc0 = cy * 64; }
  else if (cy < 12) { Wsel = Wk; wstride = 256; wc0 = (cy - 8) * 64; }
  else { Wsel = Wv; wstride = 256; wc0 = (cy - 12) * 64; }

  float acc[4][4] = {};

  for (int k0 = 0; k0 < 512; k0 += 64) {
    __syncthreads();
#pragma unroll
    for (int m = 0; m < 4; ++m) {
      int f = m * 256 + tid;
      int rr = f >> 4, dc = (f & 15) * 4;
      *reinterpret_cast<float4*>(&Xs[rr][dc]) =
          *reinterpret_cast<const float4*>(x + (size_t)(m0 + rr) * 512 + k0 + dc);
    }
#pragma unroll
    for (int m = 0; m < 4; ++m) {
      int f = m * 256 + tid;
      int rr = f >> 4, dc = (f & 15) * 4;
      *reinterpret_cast<float4*>(&Ws[rr][dc]) =
          *reinterpret_cast<const float4*>(Wsel + (size_t)(k0 + rr) * wstride + wc0 + dc);
    }
    __syncthreads();

    for (int d = 0; d < 64; d += 4) {
      float4 wv[4];
#pragma unroll
      for (int dd = 0; dd < 4; ++dd)
        wv[dd] = *reinterpret_cast<const float4*>(&Ws[d + dd][4 * tj]);
#pragma unroll
      for (int i2 = 0; i2 < 4; ++i2) {
        float4 xv = *reinterpret_cast<const float4*>(&Xs[4 * ti + i2][d]);
        acc[i2][0] += xv.x * wv[0].x + xv.y * wv[1].x + xv.z * wv[2].x + xv.w * wv[3].x;
        acc[i2][1] += xv.x * wv[0].y + xv.y * wv[1].y + xv.z * wv[2].y + xv.w * wv[3].y;
        acc[i2][2] += xv.x * wv[0].z + xv.y * wv[1].z + xv.z * wv[2].z + xv.w * wv[3].z;
        acc[i2][3] += xv.x * wv[0].w + xv.y * wv[1].w + xv.z * wv[2].w + xv.w * wv[3].w;
      }
    }
  }

  __syncthreads();
#pragma unroll
  for (int i2 = 0; i2 < 4; ++i2) {
    float4 v;
    v.x = acc[i2][0]; v.y = acc[i2][1]; v.z = acc[i2][2]; v.w = acc[i2][3];
    *reinterpret_cast<float4*>(&Xs[4 * ti + i2][4 * tj]) = v;
  }
  __syncthreads();

#pragma unroll
  for (int m = 0; m < 16; ++m) {
    int f = m * 256 + tid;
    int rr = f >> 6, d = f & 63;
    int row = m0 + rr, b = row >> 10, t = row & 1023;
    float val;
    if (cy < 12) {
      int dd = d & 31;
      float c = cosb[t * 32 + dd], s = sinb[t * 32 + dd];
      float v1 = Xs[rr][dd], v2 = Xs[rr][dd + 32];
      val = (d < 32) ? (v1 * c + v2 * s) : (v2 * c - v1 * s);
    } else {
      val = Xs[rr][d];
    }
    if (cy < 8)
      Q[((size_t)(b * HH + cy) * TT + t) * 64 + d] = val;
    else if (cy < 12)
      Kt[((size_t)(b * KVHN + cy - 8) * TT + t) * 64 + d] = val;
    else
      Vt[((size_t)(b * KVHN + cy - 12) * TT + t) * 64 + d] = val;
  }
}

// ---------------------------------------------------------------------------
// K2: tiled causal logits + exp (UNNORMALIZED) -> A (bf16); 1/rowsum -> invs.
// (unchanged, proven)
// ---------------------------------------------------------------------------
__global__ __launch_bounds__(256) void logits_exp_kernel(
    const float* __restrict__ Q, const float* __restrict__ Kt,
    u16* __restrict__ A, float* __restrict__ invs) {
  const int it = blockIdx.x, sys = blockIdx.y;
  const int b = sys >> 3, kvh = (sys & 7) >> 1;
  const int tid = threadIdx.x;
  const int ti = tid >> 4, tj = tid & 15;

  __shared__ float Qt[64][68];
  __shared__ float KtS[64][68];
  __shared__ float red[64][17];

  const float* Qb = Q + ((size_t)sys * TT + it * 64) * 64;
  const float* Kb = Kt + ((size_t)(b * KVHN + kvh) * TT) * 64;
  u16* Aout = A + ((size_t)sys << 20);

#pragma unroll
  for (int m = 0; m < 4; ++m) {
    int f = m * 256 + tid;
    int rr = f >> 4, dc = (f & 15) * 4;
    float4 v = *reinterpret_cast<const float4*>(Qb + (size_t)rr * 64 + dc);
    *reinterpret_cast<float4*>(&Qt[rr][dc]) = v;
  }

  float rs[4] = {0.f, 0.f, 0.f, 0.f};

  for (int jt = 0; jt <= it; ++jt) {
    __syncthreads();
#pragma unroll
    for (int m = 0; m < 4; ++m) {
      int f = m * 256 + tid;
      int rr = f >> 4, dc = (f & 15) * 4;
      float4 v = *reinterpret_cast<const float4*>(
          Kb + (size_t)(jt * 64 + rr) * 64 + dc);
      *reinterpret_cast<float4*>(&KtS[rr][dc]) = v;
    }
    __syncthreads();

    float acc[4][4] = {};
    for (int d = 0; d < 64; d += 4) {
      float4 qv[4], kv[4];
#pragma unroll
      for (int i2 = 0; i2 < 4; ++i2)
        qv[i2] = *reinterpret_cast<const float4*>(&Qt[4 * ti + i2][d]);
#pragma unroll
      for (int j2 = 0; j2 < 4; ++j2)
        kv[j2] = *reinterpret_cast<const float4*>(&KtS[4 * tj + j2][d]);
#pragma unroll
      for (int i2 = 0; i2 < 4; ++i2)
#pragma unroll
        for (int j2 = 0; j2 < 4; ++j2)
          acc[i2][j2] += qv[i2].x * kv[j2].x + qv[i2].y * kv[j2].y +
                         qv[i2].z * kv[j2].z + qv[i2].w * kv[j2].w;
    }

    int Jb = jt * 64 + 4 * tj;
#pragma unroll
    for (int ir = 0; ir < 4; ++ir) {
      int I = it * 64 + 4 * ti + ir;
      float4 ev;
      float e;
      e = (Jb + 0 <= I) ? __expf(acc[ir][0] * 0.125f) : 0.f; rs[ir] += e; ev.x = e;
      e = (Jb + 1 <= I) ? __expf(acc[ir][1] * 0.125f) : 0.f; rs[ir] += e; ev.y = e;
      e = (Jb + 2 <= I) ? __expf(acc[ir][2] * 0.125f) : 0.f; rs[ir] += e; ev.z = e;
      e = (Jb + 3 <= I) ? __expf(acc[ir][3] * 0.125f) : 0.f; rs[ir] += e; ev.w = e;
      uint2 pk;
      pk.x = (unsigned)bfr(ev.x) | ((unsigned)bfr(ev.y) << 16);
      pk.y = (unsigned)bfr(ev.z) | ((unsigned)bfr(ev.w) << 16);
      *reinterpret_cast<uint2*>(Aout + (size_t)I * 1024 + Jb) = pk;
    }
  }

  __syncthreads();
#pragma unroll
  for (int ir = 0; ir < 4; ++ir) red[4 * ti + ir][tj] = rs[ir];
  __syncthreads();
  if (tid < 64) {
    float s = 0.f;
#pragma unroll
    for (int t2 = 0; t2 < 16; ++t2) s += red[tid][t2];
    invs[sys * 1024 + it * 64 + tid] = 1.0f / s;
  }
}

// ---------------------------------------------------------------------------
// K3a: invert each (I + S*L_kk) diagonal block IN PLACE over bf16 A. (unchanged)
// ---------------------------------------------------------------------------
__global__ __launch_bounds__(256) void diaginv_kernel(
    u16* __restrict__ A, const float* __restrict__ invs) {
  const int k = blockIdx.x, sys = blockIdx.y;
  const int tid = threadIdx.x;
  const int r = tid & 63, cq = tid >> 6;

  u16* Ab = A + ((size_t)sys << 20) + (size_t)(k * 64) * 1024 + k * 64;

  __shared__ float Lt[64][65];
  __shared__ float W[64][65];
  __shared__ float sv[64];

#pragma unroll
  for (int m = 0; m < 2; ++m) {
    int f = m * 256 + tid;
    int rr = f >> 3, ch = f & 7;
    uint4 v = *reinterpret_cast<const uint4*>(Ab + (size_t)rr * 1024 + ch * 8);
    float* dst = &Lt[rr][ch * 8];
    dst[0] = bflo(v.x); dst[1] = bfhi(v.x); dst[2] = bflo(v.y); dst[3] = bfhi(v.y);
    dst[4] = bflo(v.z); dst[5] = bfhi(v.z); dst[6] = bflo(v.w); dst[7] = bfhi(v.w);
  }
  if (tid < 64) sv[tid] = invs[sys * 1024 + k * 64 + tid];
#pragma unroll
  for (int c = 0; c < 16; ++c) W[r][cq * 16 + c] = (r == cq * 16 + c) ? 1.f : 0.f;
  __syncthreads();

  for (int r2 = 0; r2 < 64; ++r2) {
    float dinv = 1.0f / (1.0f + sv[r2] * Lt[r2][r2]);
    if (r == r2) {
#pragma unroll
      for (int c = 0; c < 16; ++c) W[r2][cq * 16 + c] *= dinv;
    }
    __syncthreads();
    if (r > r2) {
      float f = sv[r] * Lt[r][r2];
#pragma unroll
      for (int c = 0; c < 16; ++c) W[r][cq * 16 + c] -= f * W[r2][cq * 16 + c];
    }
    __syncthreads();
  }

#pragma unroll
  for (int m = 0; m < 8; ++m) {
    int f = m * 256 + tid;
    int rr = f >> 5, cp = (f & 31) * 2;
    unsigned pk = (unsigned)bfr(W[rr][cp]) | ((unsigned)bfr(W[rr][cp + 1]) << 16);
    *reinterpret_cast<unsigned*>(Ab + (size_t)rr * 1024 + cp) = pk;
  }
}

// ---------------------------------------------------------------------------
// K3b: MFMA forward solve. Grid dim3(16 sys, 2 halves), 256 thr (4 waves).
// Wave w owns rows m0=w*16 (2 C-tiles of 16x16 over 32 cols). A/Minv frags
// direct from global (bf16). Y kept as hi/lo bf16 pair in global ws (block
// reads only its own cols); u hi/lo in LDS. 8 indep MFMA per jt per wave.
// ---------------------------------------------------------------------------
__global__ __launch_bounds__(256) void solve_mfma_kernel(
    const u16* __restrict__ A, const float* __restrict__ invs,
    const float* __restrict__ Vt, float* __restrict__ Yout,
    u16* __restrict__ Ybh, u16* __restrict__ Ybl) {
  const int sys = blockIdx.x, half = blockIdx.y;
  const int bb = sys >> 3, kvh = (sys & 7) >> 1;
  const int c0 = half * 32;
  const int tid = threadIdx.x;
  const int lane = tid & 63, w = tid >> 6;
  const int m0 = w * 16;
  const int ln = lane & 15, kg = lane >> 4;

  const u16* Ab = A + ((size_t)sys << 20);
  const float* Vb = Vt + ((size_t)(bb * KVHN + kvh) * TT) * 64;
  float* Yg = Yout + (size_t)sys * TT * 64;

  __shared__ u16 uh[32 * 64];
  __shared__ u16 ul[32 * 64];

  const int lcA = ln, lcB = 16 + ln;  // local cols for uh/ul
  const size_t gcA = ((size_t)(sys * 64 + c0 + ln)) << 10;       // u16 col base
  const size_t gcB = ((size_t)(sys * 64 + c0 + 16 + ln)) << 10;

  for (int k = 0; k < 16; ++k) {
    const int rg0 = k * 64;
    f32x4 z = {0.f, 0.f, 0.f, 0.f};
    f32x4 acc0a = z, acc0b = z, acc0c = z, acc0d = z;
    f32x4 acc1a = z, acc1b = z, acc1c = z, acc1d = z;

    const u16* arow = Ab + (size_t)(rg0 + m0 + ln) * 1024;

    for (int jt = 0; jt < k; ++jt) {
      bf16x8 a0 = ld8_g(arow + jt * 64 + kg * 8);
      bf16x8 a1 = ld8_g(arow + jt * 64 + 32 + kg * 8);
      const size_t o0 = (size_t)((jt * 8 + kg) << 3);
      const size_t o1 = (size_t)((jt * 8 + 4 + kg) << 3);
      bf16x8 bhA0 = ld8_g(Ybh + gcA + o0), bhA1 = ld8_g(Ybh + gcA + o1);
      bf16x8 blA0 = ld8_g(Ybl + gcA + o0), blA1 = ld8_g(Ybl + gcA + o1);
      bf16x8 bhB0 = ld8_g(Ybh + gcB + o0), bhB1 = ld8_g(Ybh + gcB + o1);
      bf16x8 blB0 = ld8_g(Ybl + gcB + o0), blB1 = ld8_g(Ybl + gcB + o1);
      acc0a = MFMA(a0, bhA0, acc0a);
      acc0b = MFMA(a1, bhA1, acc0b);
      acc0c = MFMA(a0, blA0, acc0c);
      acc0d = MFMA(a1, blA1, acc0d);
      acc1a = MFMA(a0, bhB0, acc1a);
      acc1b = MFMA(a1, bhB1, acc1b);
      acc1c = MFMA(a0, blB0, acc1c);
      acc1d = MFMA(a1, blB1, acc1d);
    }
    f32x4 acc0 = (acc0a + acc0b) + (acc0c + acc0d);
    f32x4 acc1 = (acc1a + acc1b) + (acc1c + acc1d);

    // u = V - sinv*S
    f32x4 u0, u1;
#pragma unroll
    for (int j = 0; j < 4; ++j) {
      int gr = rg0 + m0 + kg * 4 + j;
      float si = invs[sys * 1024 + gr];
      u0[j] = Vb[(size_t)gr * 64 + c0 + ln] - si * acc0[j];
      u1[j] = Vb[(size_t)gr * 64 + c0 + 16 + ln] - si * acc1[j];
    }
    const int r0 = m0 + kg * 4;
    st_split_lds(uh, ul, lcA, r0, u0);
    st_split_lds(uh, ul, lcB, r0, u1);
    __syncthreads();

    // y = Minv @ (uh + ul)
    bf16x8 ma0 = ld8_g(arow + rg0 + kg * 8);
    bf16x8 ma1 = ld8_g(arow + rg0 + 32 + kg * 8);
    f32x4 y0 = z, y1 = z;
    y0 = MFMA(ma0, ld8_lds(uh, lcA, kg), y0);
    y0 = MFMA(ma1, ld8_lds(uh, lcA, 4 + kg), y0);
    y0 = MFMA(ma0, ld8_lds(ul, lcA, kg), y0);
    y0 = MFMA(ma1, ld8_lds(ul, lcA, 4 + kg), y0);
    y1 = MFMA(ma0, ld8_lds(uh, lcB, kg), y1);
    y1 = MFMA(ma1, ld8_lds(uh, lcB, 4 + kg), y1);
    y1 = MFMA(ma0, ld8_lds(ul, lcB, kg), y1);
    y1 = MFMA(ma1, ld8_lds(ul, lcB, 4 + kg), y1);

#pragma unroll
    for (int j = 0; j < 4; ++j) {
      int gr = rg0 + m0 + kg * 4 + j;
      Yg[(size_t)gr * 64 + c0 + ln] = y0[j];
      Yg[(size_t)gr * 64 + c0 + 16 + ln] = y1[j];
    }
    const int yr0 = rg0 + m0 + kg * 4;
    st_split_g(Ybh, Ybl, gcA, yr0, y0);
    st_split_g(Ybh, Ybl, gcB, yr0, y1);
    __threadfence_block();
    __syncthreads();
  }
}

// ---------------------------------------------------------------------------
// K4: out = x + Y2d @ Wo as tiled GEMM. (unchanged, proven)
// ---------------------------------------------------------------------------
__global__ __launch_bounds__(256) void out_proj_kernel(
    const float* __restrict__ Y, const float* __restrict__ x,
    const float* __restrict__ Wo, float* __restrict__ out) {
  const int bx = blockIdx.x, by = blockIdx.y;
  const int tid = threadIdx.x;
  const int ti = tid >> 4, tj = tid & 15;
  const int m0 = bx * 64, n0 = by * 64;

  __shared__ float Ys[64][68];
  __shared__ float Ws[64][68];

  float acc[4][4] = {};

  for (int k0 = 0; k0 < 512; k0 += 64) {
    const int h = k0 >> 6;
    __syncthreads();
#pragma unroll
    for (int m = 0; m < 4; ++m) {
      int f = m * 256 + tid;
      int rr = f >> 4, dc = (f & 15) * 4;
      int row = m0 + rr, b = row >> 10, t = row & 1023;
      *reinterpret_cast<float4*>(&Ys[rr][dc]) =
          *reinterpret_cast<const float4*>(
              Y + ((size_t)(b * HH + h) * TT + t) * 64 + dc);
    }
#pragma unroll
    for (int m = 0; m < 4; ++m) {
      int f = m * 256 + tid;
      int rr = f >> 4, dc = (f & 15) * 4;
      *reinterpret_cast<float4*>(&Ws[rr][dc]) =
          *reinterpret_cast<const float4*>(Wo + (size_t)(k0 + rr) * 512 + n0 + dc);
    }
    __syncthreads();

    for (int d = 0; d < 64; d += 4) {
      float4 wv[4];
#pragma unroll
      for (int dd = 0; dd < 4; ++dd)
        wv[dd] = *reinterpret_cast<const float4*>(&Ws[d + dd][4 * tj]);
#pragma unroll
      for (int i2 = 0; i2 < 4; ++i2) {
        float4 xv = *reinterpret_cast<const float4*>(&Ys[4 * ti + i2][d]);
        acc[i2][0] += xv.x * wv[0].x + xv.y * wv[1].x + xv.z * wv[2].x + xv.w * wv[3].x;
        acc[i2][1] += xv.x * wv[0].y + xv.y * wv[1].y + xv.z * wv[2].y + xv.w * wv[3].y;
        acc[i2][2] += xv.x * wv[0].z + xv.y * wv[1].z + xv.z * wv[2].z + xv.w * wv[3].z;
        acc[i2][3] += xv.x * wv[0].w + xv.y * wv[1].w + xv.z * wv[2].w + xv.w * wv[3].w;
      }
    }
  }

#pragma unroll
  for (int i2 = 0; i2 < 4; ++i2) {
    size_t row = (size_t)(m0 + 4 * ti + i2);
    float4 xr = *reinterpret_cast<const float4*>(x + row * 512 + n0 + 4 * tj);
    float4 v;
    v.x = xr.x + acc[i2][0]; v.y = xr.y + acc[i2][1];
    v.z = xr.z + acc[i2][2]; v.w = xr.w + acc[i2][3];
    *reinterpret_cast<float4*>(out + row * 512 + n0 + 4 * tj) = v;
  }
}

// ---------------------------------------------------------------------------
extern "C" void kernel_launch(void* const* d_in, const int* in_sizes, int n_in,
                              void* d_out, int out_size, void* d_ws,
                              size_t ws_size, hipStream_t stream) {
  (void)in_sizes; (void)n_in; (void)out_size; (void)ws_size;
  const float* x = (const float*)d_in[0];
  const float* cosb = (const float*)d_in[1];
  const float* sinb = (const float*)d_in[2];
  const float* Wq = (const float*)d_in[3];
  const float* Wk = (const float*)d_in[4];
  const float* Wv = (const float*)d_in[5];
  const float* Wo = (const float*)d_in[6];
  float* out = (float*)d_out;

  float* ws = (float*)d_ws;
  float* Q = ws;                        // 1,048,576 f
  float* Kt = Q + (size_t)1048576;      //   524,288 f
  float* Vt = Kt + (size_t)524288;      //   524,288 f
  float* Yb = Vt + (size_t)524288;      // 1,048,576 f
  float* invs = Yb + (size_t)1048576;   //    16,384 f
  u16* A = (u16*)(invs + 16384);        // 16,777,216 u16 = 32 MB
  u16* Ybh = A + (size_t)16777216;      //  1,048,576 u16 = 2 MB
  u16* Ybl = Ybh + (size_t)1048576;     //  1,048,576 u16 = 2 MB  (~48 MB total)

  qkv_kernel<<<dim3(32, 16), 256, 0, stream>>>(x, cosb, sinb, Wq, Wk, Wv, Q, Kt, Vt);
  logits_exp_kernel<<<dim3(16, 16), 256, 0, stream>>>(Q, Kt, A, invs);
  diaginv_kernel<<<dim3(16, 16), 256, 0, stream>>>(A, invs);
  solve_mfma_kernel<<<dim3(16, 2), 256, 0, stream>>>(A, invs, Vt, Yb, Ybh, Ybl);
  out_proj_kernel<<<dim3(32, 8), 256, 0, stream>>>(Yb, x, Wo, out);
}

// Round 11
// 267.046 us; speedup vs baseline: 1.4018x; 1.4018x over previous
//
#include <hip/hip_runtime.h>
#include <cmath>

#define TT 1024
#define HH 8
#define KVHN 4

typedef unsigned short u16;
typedef __attribute__((ext_vector_type(8))) short bf16x8;
typedef __attribute__((ext_vector_type(4))) float f32x4;

#define MFMA(a, b, c) __builtin_amdgcn_mfma_f32_16x16x32_bf16(a, b, c, 0, 0, 0)

__device__ __forceinline__ float bflo(unsigned u) { return __uint_as_float(u << 16); }
__device__ __forceinline__ float bfhi(unsigned u) { return __uint_as_float(u & 0xffff0000u); }
__device__ __forceinline__ u16 bfr(float f) {
  unsigned u = __float_as_uint(f);
  return (u16)((u + 0x7fffu + ((u >> 16) & 1u)) >> 16);
}

__device__ __forceinline__ bf16x8 ld8_g(const u16* __restrict__ p) {
  uint4 v = *reinterpret_cast<const uint4*>(p);
  return __builtin_bit_cast(bf16x8, v);
}
// LDS tile: 64 u16 per col, chunk-swizzled (validated round 10)
__device__ __forceinline__ bf16x8 ld8_lds(const u16* s, int col, int k8) {
  const uint4* p = reinterpret_cast<const uint4*>(s);
  return __builtin_bit_cast(bf16x8, p[col * 8 + (k8 ^ (col & 7))]);
}
__device__ __forceinline__ void st_split_lds(u16* sh, u16* sl, int col, int r0,
                                             f32x4 v) {
  u16 hh[4], ll[4];
#pragma unroll
  for (int j = 0; j < 4; ++j) {
    u16 hb = bfr(v[j]);
    hh[j] = hb;
    ll[j] = bfr(v[j] - __uint_as_float((unsigned)hb << 16));
  }
  uint2 ph, pl;
  ph.x = (unsigned)hh[0] | ((unsigned)hh[1] << 16);
  ph.y = (unsigned)hh[2] | ((unsigned)hh[3] << 16);
  pl.x = (unsigned)ll[0] | ((unsigned)ll[1] << 16);
  pl.y = (unsigned)ll[2] | ((unsigned)ll[3] << 16);
  int idx = col * 64 + (((r0 >> 3) ^ (col & 7)) << 3) + (r0 & 7);
  *reinterpret_cast<uint2*>(sh + idx) = ph;
  *reinterpret_cast<uint2*>(sl + idx) = pl;
}

// ---------------------------------------------------------------------------
// K1: QKV projection as tiled GEMM + fused RoPE. (unchanged, proven)
// ---------------------------------------------------------------------------
__global__ __launch_bounds__(256) void qkv_kernel(
    const float* __restrict__ x, const float* __restrict__ cosb,
    const float* __restrict__ sinb, const float* __restrict__ Wq,
    const float* __restrict__ Wk, const float* __restrict__ Wv,
    float* __restrict__ Q, float* __restrict__ Kt, float* __restrict__ Vt) {
  const int bx = blockIdx.x, cy = blockIdx.y;
  const int tid = threadIdx.x;
  const int ti = tid >> 4, tj = tid & 15;
  const int m0 = bx * 64;

  __shared__ float Xs[64][68];
  __shared__ float Ws[64][68];

  const float* Wsel;
  int wstride, wc0;
  if (cy < 8) { Wsel = Wq; wstride = 512; wc0 = cy * 64; }
  else if (cy < 12) { Wsel = Wk; wstride = 256; wc0 = (cy - 8) * 64; }
  else { Wsel = Wv; wstride = 256; wc0 = (cy - 12) * 64; }

  float acc[4][4] = {};

  for (int k0 = 0; k0 < 512; k0 += 64) {
    __syncthreads();
#pragma unroll
    for (int m = 0; m < 4; ++m) {
      int f = m * 256 + tid;
      int rr = f >> 4, dc = (f & 15) * 4;
      *reinterpret_cast<float4*>(&Xs[rr][dc]) =
          *reinterpret_cast<const float4*>(x + (size_t)(m0 + rr) * 512 + k0 + dc);
    }
#pragma unroll
    for (int m = 0; m < 4; ++m) {
      int f = m * 256 + tid;
      int rr = f >> 4, dc = (f & 15) * 4;
      *reinterpret_cast<float4*>(&Ws[rr][dc]) =
          *reinterpret_cast<const float4*>(Wsel + (size_t)(k0 + rr) * wstride + wc0 + dc);
    }
    __syncthreads();

    for (int d = 0; d < 64; d += 4) {
      float4 wv[4];
#pragma unroll
      for (int dd = 0; dd < 4; ++dd)
        wv[dd] = *reinterpret_cast<const float4*>(&Ws[d + dd][4 * tj]);
#pragma unroll
      for (int i2 = 0; i2 < 4; ++i2) {
        float4 xv = *reinterpret_cast<const float4*>(&Xs[4 * ti + i2][d]);
        acc[i2][0] += xv.x * wv[0].x + xv.y * wv[1].x + xv.z * wv[2].x + xv.w * wv[3].x;
        acc[i2][1] += xv.x * wv[0].y + xv.y * wv[1].y + xv.z * wv[2].y + xv.w * wv[3].y;
        acc[i2][2] += xv.x * wv[0].z + xv.y * wv[1].z + xv.z * wv[2].z + xv.w * wv[3].z;
        acc[i2][3] += xv.x * wv[0].w + xv.y * wv[1].w + xv.z * wv[2].w + xv.w * wv[3].w;
      }
    }
  }

  __syncthreads();
#pragma unroll
  for (int i2 = 0; i2 < 4; ++i2) {
    float4 v;
    v.x = acc[i2][0]; v.y = acc[i2][1]; v.z = acc[i2][2]; v.w = acc[i2][3];
    *reinterpret_cast<float4*>(&Xs[4 * ti + i2][4 * tj]) = v;
  }
  __syncthreads();

#pragma unroll
  for (int m = 0; m < 16; ++m) {
    int f = m * 256 + tid;
    int rr = f >> 6, d = f & 63;
    int row = m0 + rr, b = row >> 10, t = row & 1023;
    float val;
    if (cy < 12) {
      int dd = d & 31;
      float c = cosb[t * 32 + dd], s = sinb[t * 32 + dd];
      float v1 = Xs[rr][dd], v2 = Xs[rr][dd + 32];
      val = (d < 32) ? (v1 * c + v2 * s) : (v2 * c - v1 * s);
    } else {
      val = Xs[rr][d];
    }
    if (cy < 8)
      Q[((size_t)(b * HH + cy) * TT + t) * 64 + d] = val;
    else if (cy < 12)
      Kt[((size_t)(b * KVHN + cy - 8) * TT + t) * 64 + d] = val;
    else
      Vt[((size_t)(b * KVHN + cy - 12) * TT + t) * 64 + d] = val;
  }
}

// ---------------------------------------------------------------------------
// K2: tiled causal logits + exp (UNNORMALIZED) -> A (bf16); 1/rowsum -> invs.
// (unchanged, proven)
// ---------------------------------------------------------------------------
__global__ __launch_bounds__(256) void logits_exp_kernel(
    const float* __restrict__ Q, const float* __restrict__ Kt,
    u16* __restrict__ A, float* __restrict__ invs) {
  const int it = blockIdx.x, sys = blockIdx.y;
  const int b = sys >> 3, kvh = (sys & 7) >> 1;
  const int tid = threadIdx.x;
  const int ti = tid >> 4, tj = tid & 15;

  __shared__ float Qt[64][68];
  __shared__ float KtS[64][68];
  __shared__ float red[64][17];

  const float* Qb = Q + ((size_t)sys * TT + it * 64) * 64;
  const float* Kb = Kt + ((size_t)(b * KVHN + kvh) * TT) * 64;
  u16* Aout = A + ((size_t)sys << 20);

#pragma unroll
  for (int m = 0; m < 4; ++m) {
    int f = m * 256 + tid;
    int rr = f >> 4, dc = (f & 15) * 4;
    float4 v = *reinterpret_cast<const float4*>(Qb + (size_t)rr * 64 + dc);
    *reinterpret_cast<float4*>(&Qt[rr][dc]) = v;
  }

  float rs[4] = {0.f, 0.f, 0.f, 0.f};

  for (int jt = 0; jt <= it; ++jt) {
    __syncthreads();
#pragma unroll
    for (int m = 0; m < 4; ++m) {
      int f = m * 256 + tid;
      int rr = f >> 4, dc = (f & 15) * 4;
      float4 v = *reinterpret_cast<const float4*>(
          Kb + (size_t)(jt * 64 + rr) * 64 + dc);
      *reinterpret_cast<float4*>(&KtS[rr][dc]) = v;
    }
    __syncthreads();

    float acc[4][4] = {};
    for (int d = 0; d < 64; d += 4) {
      float4 qv[4], kv[4];
#pragma unroll
      for (int i2 = 0; i2 < 4; ++i2)
        qv[i2] = *reinterpret_cast<const float4*>(&Qt[4 * ti + i2][d]);
#pragma unroll
      for (int j2 = 0; j2 < 4; ++j2)
        kv[j2] = *reinterpret_cast<const float4*>(&KtS[4 * tj + j2][d]);
#pragma unroll
      for (int i2 = 0; i2 < 4; ++i2)
#pragma unroll
        for (int j2 = 0; j2 < 4; ++j2)
          acc[i2][j2] += qv[i2].x * kv[j2].x + qv[i2].y * kv[j2].y +
                         qv[i2].z * kv[j2].z + qv[i2].w * kv[j2].w;
    }

    int Jb = jt * 64 + 4 * tj;
#pragma unroll
    for (int ir = 0; ir < 4; ++ir) {
      int I = it * 64 + 4 * ti + ir;
      float4 ev;
      float e;
      e = (Jb + 0 <= I) ? __expf(acc[ir][0] * 0.125f) : 0.f; rs[ir] += e; ev.x = e;
      e = (Jb + 1 <= I) ? __expf(acc[ir][1] * 0.125f) : 0.f; rs[ir] += e; ev.y = e;
      e = (Jb + 2 <= I) ? __expf(acc[ir][2] * 0.125f) : 0.f; rs[ir] += e; ev.z = e;
      e = (Jb + 3 <= I) ? __expf(acc[ir][3] * 0.125f) : 0.f; rs[ir] += e; ev.w = e;
      uint2 pk;
      pk.x = (unsigned)bfr(ev.x) | ((unsigned)bfr(ev.y) << 16);
      pk.y = (unsigned)bfr(ev.z) | ((unsigned)bfr(ev.w) << 16);
      *reinterpret_cast<uint2*>(Aout + (size_t)I * 1024 + Jb) = pk;
    }
  }

  __syncthreads();
#pragma unroll
  for (int ir = 0; ir < 4; ++ir) red[4 * ti + ir][tj] = rs[ir];
  __syncthreads();
  if (tid < 64) {
    float s = 0.f;
#pragma unroll
    for (int t2 = 0; t2 < 16; ++t2) s += red[tid][t2];
    invs[sys * 1024 + it * 64 + tid] = 1.0f / s;
  }
}

// ---------------------------------------------------------------------------
// K3a: invert each (I + S*L_kk) diagonal block IN PLACE over bf16 A. (unchanged)
// ---------------------------------------------------------------------------
__global__ __launch_bounds__(256) void diaginv_kernel(
    u16* __restrict__ A, const float* __restrict__ invs) {
  const int k = blockIdx.x, sys = blockIdx.y;
  const int tid = threadIdx.x;
  const int r = tid & 63, cq = tid >> 6;

  u16* Ab = A + ((size_t)sys << 20) + (size_t)(k * 64) * 1024 + k * 64;

  __shared__ float Lt[64][65];
  __shared__ float W[64][65];
  __shared__ float sv[64];

#pragma unroll
  for (int m = 0; m < 2; ++m) {
    int f = m * 256 + tid;
    int rr = f >> 3, ch = f & 7;
    uint4 v = *reinterpret_cast<const uint4*>(Ab + (size_t)rr * 1024 + ch * 8);
    float* dst = &Lt[rr][ch * 8];
    dst[0] = bflo(v.x); dst[1] = bfhi(v.x); dst[2] = bflo(v.y); dst[3] = bfhi(v.y);
    dst[4] = bflo(v.z); dst[5] = bfhi(v.z); dst[6] = bflo(v.w); dst[7] = bfhi(v.w);
  }
  if (tid < 64) sv[tid] = invs[sys * 1024 + k * 64 + tid];
#pragma unroll
  for (int c = 0; c < 16; ++c) W[r][cq * 16 + c] = (r == cq * 16 + c) ? 1.f : 0.f;
  __syncthreads();

  for (int r2 = 0; r2 < 64; ++r2) {
    float dinv = 1.0f / (1.0f + sv[r2] * Lt[r2][r2]);
    if (r == r2) {
#pragma unroll
      for (int c = 0; c < 16; ++c) W[r2][cq * 16 + c] *= dinv;
    }
    __syncthreads();
    if (r > r2) {
      float f = sv[r] * Lt[r][r2];
#pragma unroll
      for (int c = 0; c < 16; ++c) W[r][cq * 16 + c] -= f * W[r2][cq * 16 + c];
    }
    __syncthreads();
  }

#pragma unroll
  for (int m = 0; m < 8; ++m) {
    int f = m * 256 + tid;
    int rr = f >> 5, cp = (f & 31) * 2;
    unsigned pk = (unsigned)bfr(W[rr][cp]) | ((unsigned)bfr(W[rr][cp + 1]) << 16);
    *reinterpret_cast<unsigned*>(Ab + (size_t)rr * 1024 + cp) = pk;
  }
}

// ---------------------------------------------------------------------------
// K3b: right-looking MFMA solve. Grid dim3(16 sys, 4 col-quarters), 1024 thr
// (16 waves, 4/SIMD). Residual U (f32) in LDS; per k-step: diag solve by
// waves 0-3, then ALL waves apply U[i] += A(i,k)*y_k for i>k (disjoint units).
// Only the current y tile (64x16 hi/lo bf16, 4KB) is shared between steps.
// ---------------------------------------------------------------------------
__global__ __launch_bounds__(1024) void solve_mfma_kernel(
    const u16* __restrict__ A, const float* __restrict__ invs,
    const float* __restrict__ Vt, float* __restrict__ Yout) {
  const int sys = blockIdx.x, cq = blockIdx.y;
  const int bb = sys >> 3, kvh = (sys & 7) >> 1;
  const int c0 = cq * 16;
  const int tid = threadIdx.x;
  const int lane = tid & 63, w = tid >> 6;  // 16 waves
  const int ln = lane & 15, kg = lane >> 4;

  const u16* Ab = A + ((size_t)sys << 20);
  const float* Vb = Vt + ((size_t)(bb * KVHN + kvh) * TT) * 64;
  float* Yg = Yout + (size_t)sys * TT * 64;

  __shared__ float U[16][1028];            // [col][row] residual, 65.8 KB
  __shared__ u16 yh[16 * 64], yl[16 * 64]; // current y tile hi/lo
  __shared__ u16 uh[16 * 64], ul[16 * 64]; // u tile hi/lo

  // zero U
  {
    float* Uf = &U[0][0];
    for (int i = tid; i < 16 * 1028; i += 1024) Uf[i] = 0.f;
  }
  __syncthreads();

  for (int k = 0; k < 16; ++k) {
    const int rg0 = k * 64;

    // Phase 1 (waves 0-3): u = V - sinv * U[k-tile]
    if (w < 4) {
      const int m0 = w * 16;
      f32x4 u;
#pragma unroll
      for (int j = 0; j < 4; ++j) {
        int gr = rg0 + m0 + kg * 4 + j;
        float si = invs[sys * 1024 + gr];
        u[j] = Vb[(size_t)gr * 64 + c0 + ln] - si * U[ln][gr];
      }
      st_split_lds(uh, ul, ln, m0 + kg * 4, u);
    }
    __syncthreads();

    // Phase 2 (waves 0-3): y = Minv @ (uh + ul); publish y tile
    if (w < 4) {
      const int m0 = w * 16;
      const u16* mrow = Ab + (size_t)(rg0 + m0 + ln) * 1024 + rg0;
      bf16x8 ma0 = ld8_g(mrow + kg * 8);
      bf16x8 ma1 = ld8_g(mrow + 32 + kg * 8);
      f32x4 y = {0.f, 0.f, 0.f, 0.f};
      y = MFMA(ma0, ld8_lds(uh, ln, kg), y);
      y = MFMA(ma1, ld8_lds(uh, ln, 4 + kg), y);
      y = MFMA(ma0, ld8_lds(ul, ln, kg), y);
      y = MFMA(ma1, ld8_lds(ul, ln, 4 + kg), y);
#pragma unroll
      for (int j = 0; j < 4; ++j)
        Yg[(size_t)(rg0 + m0 + kg * 4 + j) * 64 + c0 + ln] = y[j];
      st_split_lds(yh, yl, ln, m0 + kg * 4, y);
    }
    __syncthreads();

    // Phase 3 (all waves): U[i] += A(i,k) * y_k  for i > k
    const int nu = (15 - k) * 4;
    for (int un = w; un < nu; un += 16) {
      const int i = k + 1 + (un >> 2), rq = un & 3;
      const u16* arow = Ab + (size_t)(i * 64 + rq * 16 + ln) * 1024 + rg0;
      bf16x8 a0 = ld8_g(arow + kg * 8);
      bf16x8 a1 = ld8_g(arow + 32 + kg * 8);
      f32x4 s = {0.f, 0.f, 0.f, 0.f};
      s = MFMA(a0, ld8_lds(yh, ln, kg), s);
      s = MFMA(a1, ld8_lds(yh, ln, 4 + kg), s);
      s = MFMA(a0, ld8_lds(yl, ln, kg), s);
      s = MFMA(a1, ld8_lds(yl, ln, 4 + kg), s);
      const int rb = i * 64 + rq * 16 + kg * 4;
#pragma unroll
      for (int j = 0; j < 4; ++j) U[ln][rb + j] += s[j];
    }
    __syncthreads();
  }
}

// ---------------------------------------------------------------------------
// K4: out = x + Y2d @ Wo as tiled GEMM. (unchanged, proven)
// ---------------------------------------------------------------------------
__global__ __launch_bounds__(256) void out_proj_kernel(
    const float* __restrict__ Y, const float* __restrict__ x,
    const float* __restrict__ Wo, float* __restrict__ out) {
  const int bx = blockIdx.x, by = blockIdx.y;
  const int tid = threadIdx.x;
  const int ti = tid >> 4, tj = tid & 15;
  const int m0 = bx * 64, n0 = by * 64;

  __shared__ float Ys[64][68];
  __shared__ float Ws[64][68];

  float acc[4][4] = {};

  for (int k0 = 0; k0 < 512; k0 += 64) {
    const int h = k0 >> 6;
    __syncthreads();
#pragma unroll
    for (int m = 0; m < 4; ++m) {
      int f = m * 256 + tid;
      int rr = f >> 4, dc = (f & 15) * 4;
      int row = m0 + rr, b = row >> 10, t = row & 1023;
      *reinterpret_cast<float4*>(&Ys[rr][dc]) =
          *reinterpret_cast<const float4*>(
              Y + ((size_t)(b * HH + h) * TT + t) * 64 + dc);
    }
#pragma unroll
    for (int m = 0; m < 4; ++m) {
      int f = m * 256 + tid;
      int rr = f >> 4, dc = (f & 15) * 4;
      *reinterpret_cast<float4*>(&Ws[rr][dc]) =
          *reinterpret_cast<const float4*>(Wo + (size_t)(k0 + rr) * 512 + n0 + dc);
    }
    __syncthreads();

    for (int d = 0; d < 64; d += 4) {
      float4 wv[4];
#pragma unroll
      for (int dd = 0; dd < 4; ++dd)
        wv[dd] = *reinterpret_cast<const float4*>(&Ws[d + dd][4 * tj]);
#pragma unroll
      for (int i2 = 0; i2 < 4; ++i2) {
        float4 xv = *reinterpret_cast<const float4*>(&Ys[4 * ti + i2][d]);
        acc[i2][0] += xv.x * wv[0].x + xv.y * wv[1].x + xv.z * wv[2].x + xv.w * wv[3].x;
        acc[i2][1] += xv.x * wv[0].y + xv.y * wv[1].y + xv.z * wv[2].y + xv.w * wv[3].y;
        acc[i2][2] += xv.x * wv[0].z + xv.y * wv[1].z + xv.z * wv[2].z + xv.w * wv[3].z;
        acc[i2][3] += xv.x * wv[0].w + xv.y * wv[1].w + xv.z * wv[2].w + xv.w * wv[3].w;
      }
    }
  }

#pragma unroll
  for (int i2 = 0; i2 < 4; ++i2) {
    size_t row = (size_t)(m0 + 4 * ti + i2);
    float4 xr = *reinterpret_cast<const float4*>(x + row * 512 + n0 + 4 * tj);
    float4 v;
    v.x = xr.x + acc[i2][0]; v.y = xr.y + acc[i2][1];
    v.z = xr.z + acc[i2][2]; v.w = xr.w + acc[i2][3];
    *reinterpret_cast<float4*>(out + row * 512 + n0 + 4 * tj) = v;
  }
}

// ---------------------------------------------------------------------------
extern "C" void kernel_launch(void* const* d_in, const int* in_sizes, int n_in,
                              void* d_out, int out_size, void* d_ws,
                              size_t ws_size, hipStream_t stream) {
  (void)in_sizes; (void)n_in; (void)out_size; (void)ws_size;
  const float* x = (const float*)d_in[0];
  const float* cosb = (const float*)d_in[1];
  const float* sinb = (const float*)d_in[2];
  const float* Wq = (const float*)d_in[3];
  const float* Wk = (const float*)d_in[4];
  const float* Wv = (const float*)d_in[5];
  const float* Wo = (const float*)d_in[6];
  float* out = (float*)d_out;

  float* ws = (float*)d_ws;
  float* Q = ws;                        // 1,048,576 f
  float* Kt = Q + (size_t)1048576;      //   524,288 f
  float* Vt = Kt + (size_t)524288;      //   524,288 f
  float* Yb = Vt + (size_t)524288;      // 1,048,576 f
  float* invs = Yb + (size_t)1048576;   //    16,384 f
  u16* A = (u16*)(invs + 16384);        // 16,777,216 u16 = 32 MB (~44 MB total)

  qkv_kernel<<<dim3(32, 16), 256, 0, stream>>>(x, cosb, sinb, Wq, Wk, Wv, Q, Kt, Vt);
  logits_exp_kernel<<<dim3(16, 16), 256, 0, stream>>>(Q, Kt, A, invs);
  diaginv_kernel<<<dim3(16, 16), 256, 0, stream>>>(A, invs);
  solve_mfma_kernel<<<dim3(16, 4), 1024, 0, stream>>>(A, invs, Vt, Yb);
  out_proj_kernel<<<dim3(32, 8), 256, 0, stream>>>(Yb, x, Wo, out);
}

// Round 12
// 232.828 us; speedup vs baseline: 1.6078x; 1.1470x over previous
//
#include <hip/hip_runtime.h>
#include <cmath>

#define TT 1024
#define HH 8
#define KVHN 4

typedef unsigned short u16;
typedef __attribute__((ext_vector_type(8))) short bf16x8;
typedef __attribute__((ext_vector_type(4))) float f32x4;

#define MFMA(a, b, c) __builtin_amdgcn_mfma_f32_16x16x32_bf16(a, b, c, 0, 0, 0)

__device__ __forceinline__ float bflo(unsigned u) { return __uint_as_float(u << 16); }
__device__ __forceinline__ float bfhi(unsigned u) { return __uint_as_float(u & 0xffff0000u); }
__device__ __forceinline__ u16 bfr(float f) {
  unsigned u = __float_as_uint(f);
  return (u16)((u + 0x7fffu + ((u >> 16) & 1u)) >> 16);
}

__device__ __forceinline__ bf16x8 ld8_g(const u16* __restrict__ p) {
  uint4 v = *reinterpret_cast<const uint4*>(p);
  return __builtin_bit_cast(bf16x8, v);
}
// LDS tile: 64 u16 per col, chunk-swizzled (validated round 10)
__device__ __forceinline__ bf16x8 ld8_lds(const u16* s, int col, int k8) {
  const uint4* p = reinterpret_cast<const uint4*>(s);
  return __builtin_bit_cast(bf16x8, p[col * 8 + (k8 ^ (col & 7))]);
}
__device__ __forceinline__ void st_split_lds(u16* sh, u16* sl, int col, int r0,
                                             f32x4 v) {
  u16 hh[4], ll[4];
#pragma unroll
  for (int j = 0; j < 4; ++j) {
    u16 hb = bfr(v[j]);
    hh[j] = hb;
    ll[j] = bfr(v[j] - __uint_as_float((unsigned)hb << 16));
  }
  uint2 ph, pl;
  ph.x = (unsigned)hh[0] | ((unsigned)hh[1] << 16);
  ph.y = (unsigned)hh[2] | ((unsigned)hh[3] << 16);
  pl.x = (unsigned)ll[0] | ((unsigned)ll[1] << 16);
  pl.y = (unsigned)ll[2] | ((unsigned)ll[3] << 16);
  int idx = col * 64 + (((r0 >> 3) ^ (col & 7)) << 3) + (r0 & 7);
  *reinterpret_cast<uint2*>(sh + idx) = ph;
  *reinterpret_cast<uint2*>(sl + idx) = pl;
}
// load 8 consecutive f32 at p, split into hi/lo bf16x8 fragments
__device__ __forceinline__ void cvt8(const float* __restrict__ p, bf16x8& h,
                                     bf16x8& l) {
  float4 a = *reinterpret_cast<const float4*>(p);
  float4 b = *reinterpret_cast<const float4*>(p + 4);
  float v[8] = {a.x, a.y, a.z, a.w, b.x, b.y, b.z, b.w};
  unsigned hh[8], ll[8];
#pragma unroll
  for (int j = 0; j < 8; ++j) {
    u16 hb = bfr(v[j]);
    hh[j] = hb;
    ll[j] = bfr(v[j] - __uint_as_float((unsigned)hb << 16));
  }
  uint4 H, L;
  H.x = hh[0] | (hh[1] << 16); H.y = hh[2] | (hh[3] << 16);
  H.z = hh[4] | (hh[5] << 16); H.w = hh[6] | (hh[7] << 16);
  L.x = ll[0] | (ll[1] << 16); L.y = ll[2] | (ll[3] << 16);
  L.z = ll[4] | (ll[5] << 16); L.w = ll[6] | (ll[7] << 16);
  h = __builtin_bit_cast(bf16x8, H);
  l = __builtin_bit_cast(bf16x8, L);
}

// ---------------------------------------------------------------------------
// K1: QKV projection as tiled GEMM + fused RoPE. (unchanged, proven)
// ---------------------------------------------------------------------------
__global__ __launch_bounds__(256) void qkv_kernel(
    const float* __restrict__ x, const float* __restrict__ cosb,
    const float* __restrict__ sinb, const float* __restrict__ Wq,
    const float* __restrict__ Wk, const float* __restrict__ Wv,
    float* __restrict__ Q, float* __restrict__ Kt, float* __restrict__ Vt) {
  const int bx = blockIdx.x, cy = blockIdx.y;
  const int tid = threadIdx.x;
  const int ti = tid >> 4, tj = tid & 15;
  const int m0 = bx * 64;

  __shared__ float Xs[64][68];
  __shared__ float Ws[64][68];

  const float* Wsel;
  int wstride, wc0;
  if (cy < 8) { Wsel = Wq; wstride = 512; wc0 = cy * 64; }
  else if (cy < 12) { Wsel = Wk; wstride = 256; wc0 = (cy - 8) * 64; }
  else { Wsel = Wv; wstride = 256; wc0 = (cy - 12) * 64; }

  float acc[4][4] = {};

  for (int k0 = 0; k0 < 512; k0 += 64) {
    __syncthreads();
#pragma unroll
    for (int m = 0; m < 4; ++m) {
      int f = m * 256 + tid;
      int rr = f >> 4, dc = (f & 15) * 4;
      *reinterpret_cast<float4*>(&Xs[rr][dc]) =
          *reinterpret_cast<const float4*>(x + (size_t)(m0 + rr) * 512 + k0 + dc);
    }
#pragma unroll
    for (int m = 0; m < 4; ++m) {
      int f = m * 256 + tid;
      int rr = f >> 4, dc = (f & 15) * 4;
      *reinterpret_cast<float4*>(&Ws[rr][dc]) =
          *reinterpret_cast<const float4*>(Wsel + (size_t)(k0 + rr) * wstride + wc0 + dc);
    }
    __syncthreads();

    for (int d = 0; d < 64; d += 4) {
      float4 wv[4];
#pragma unroll
      for (int dd = 0; dd < 4; ++dd)
        wv[dd] = *reinterpret_cast<const float4*>(&Ws[d + dd][4 * tj]);
#pragma unroll
      for (int i2 = 0; i2 < 4; ++i2) {
        float4 xv = *reinterpret_cast<const float4*>(&Xs[4 * ti + i2][d]);
        acc[i2][0] += xv.x * wv[0].x + xv.y * wv[1].x + xv.z * wv[2].x + xv.w * wv[3].x;
        acc[i2][1] += xv.x * wv[0].y + xv.y * wv[1].y + xv.z * wv[2].y + xv.w * wv[3].y;
        acc[i2][2] += xv.x * wv[0].z + xv.y * wv[1].z + xv.z * wv[2].z + xv.w * wv[3].z;
        acc[i2][3] += xv.x * wv[0].w + xv.y * wv[1].w + xv.z * wv[2].w + xv.w * wv[3].w;
      }
    }
  }

  __syncthreads();
#pragma unroll
  for (int i2 = 0; i2 < 4; ++i2) {
    float4 v;
    v.x = acc[i2][0]; v.y = acc[i2][1]; v.z = acc[i2][2]; v.w = acc[i2][3];
    *reinterpret_cast<float4*>(&Xs[4 * ti + i2][4 * tj]) = v;
  }
  __syncthreads();

#pragma unroll
  for (int m = 0; m < 16; ++m) {
    int f = m * 256 + tid;
    int rr = f >> 6, d = f & 63;
    int row = m0 + rr, b = row >> 10, t = row & 1023;
    float val;
    if (cy < 12) {
      int dd = d & 31;
      float c = cosb[t * 32 + dd], s = sinb[t * 32 + dd];
      float v1 = Xs[rr][dd], v2 = Xs[rr][dd + 32];
      val = (d < 32) ? (v1 * c + v2 * s) : (v2 * c - v1 * s);
    } else {
      val = Xs[rr][d];
    }
    if (cy < 8)
      Q[((size_t)(b * HH + cy) * TT + t) * 64 + d] = val;
    else if (cy < 12)
      Kt[((size_t)(b * KVHN + cy - 8) * TT + t) * 64 + d] = val;
    else
      Vt[((size_t)(b * KVHN + cy - 12) * TT + t) * 64 + d] = val;
  }
}

// ---------------------------------------------------------------------------
// K2a: MFMA causal logits + exp (UNNORMALIZED) -> A (bf16); per-tile row
// partial sums -> part[sys][jt][row]. Grid (136 lower-tri tile pairs, 16 sys),
// 256 thr (4 waves); wave = 16 q-rows x 64 k-cols. Q/K hi/lo bf16 from L2.
// ---------------------------------------------------------------------------
__global__ __launch_bounds__(256) void logits_mfma_kernel(
    const float* __restrict__ Q, const float* __restrict__ Kt,
    u16* __restrict__ A, float* __restrict__ part) {
  const int n = blockIdx.x, sys = blockIdx.y;
  int it = 0;
  while ((it + 1) * (it + 2) / 2 <= n) ++it;
  const int jt = n - it * (it + 1) / 2;
  const int b = sys >> 3, kvh = (sys & 7) >> 1;
  const int tid = threadIdx.x;
  const int lane = tid & 63, w = tid >> 6;
  const int ln = lane & 15, kg = lane >> 4;
  const int m0 = w * 16;

  const float* Qr = Q + ((size_t)sys * TT + it * 64 + m0 + ln) * 64;
  const float* Kb = Kt + ((size_t)(b * KVHN + kvh) * TT + jt * 64) * 64;
  u16* Aout = A + ((size_t)sys << 20);

  bf16x8 qh0, ql0, qh1, ql1;
  cvt8(Qr + kg * 8, qh0, ql0);
  cvt8(Qr + 32 + kg * 8, qh1, ql1);

  f32x4 acc[4];
#pragma unroll
  for (int ct = 0; ct < 4; ++ct) {
    const float* Kr = Kb + (size_t)(ct * 16 + ln) * 64;
    bf16x8 kh0, kl0, kh1, kl1;
    cvt8(Kr + kg * 8, kh0, kl0);
    cvt8(Kr + 32 + kg * 8, kh1, kl1);
    f32x4 a = {0.f, 0.f, 0.f, 0.f};
    a = MFMA(qh0, kh0, a);
    a = MFMA(qh1, kh1, a);
    a = MFMA(qh0, kl0, a);
    a = MFMA(qh1, kl1, a);
    a = MFMA(ql0, kh0, a);
    a = MFMA(ql1, kh1, a);
    acc[ct] = a;
  }

  const int grow0 = it * 64 + m0;
  const bool full = (jt < it);
  float s[4] = {0.f, 0.f, 0.f, 0.f};
#pragma unroll
  for (int ct = 0; ct < 4; ++ct) {
    int col = jt * 64 + ct * 16 + ln;
#pragma unroll
    for (int j = 0; j < 4; ++j) {
      int row = grow0 + kg * 4 + j;
      float e = (full || col <= row) ? __expf(acc[ct][j] * 0.125f) : 0.f;
      s[j] += e;
      Aout[(size_t)row * 1024 + col] = bfr(e);
    }
  }

  // reduce row sums across ln (low 4 lane bits)
#pragma unroll
  for (int off = 1; off < 16; off <<= 1) {
#pragma unroll
    for (int j = 0; j < 4; ++j) s[j] += __shfl_xor(s[j], off);
  }
  if (ln == 0) {
#pragma unroll
    for (int j = 0; j < 4; ++j)
      part[((size_t)(sys * 16 + jt)) * 1024 + grow0 + kg * 4 + j] = s[j];
  }
}

// ---------------------------------------------------------------------------
// K2b: invs[row] = 1 / sum_jt part[sys][jt][row]. Grid 16 sys, 1024 thr.
// ---------------------------------------------------------------------------
__global__ __launch_bounds__(1024) void invs_kernel(
    const float* __restrict__ part, float* __restrict__ invs) {
  const int sys = blockIdx.x, r = threadIdx.x;
  const int itop = r >> 6;
  float s = 0.f;
  for (int jt = 0; jt <= itop; ++jt)
    s += part[((size_t)(sys * 16 + jt)) * 1024 + r];
  invs[sys * 1024 + r] = 1.0f / s;
}

// ---------------------------------------------------------------------------
// K3a: invert each (I + S*L_kk) diagonal block IN PLACE over bf16 A. (unchanged)
// ---------------------------------------------------------------------------
__global__ __launch_bounds__(256) void diaginv_kernel(
    u16* __restrict__ A, const float* __restrict__ invs) {
  const int k = blockIdx.x, sys = blockIdx.y;
  const int tid = threadIdx.x;
  const int r = tid & 63, cq = tid >> 6;

  u16* Ab = A + ((size_t)sys << 20) + (size_t)(k * 64) * 1024 + k * 64;

  __shared__ float Lt[64][65];
  __shared__ float W[64][65];
  __shared__ float sv[64];

#pragma unroll
  for (int m = 0; m < 2; ++m) {
    int f = m * 256 + tid;
    int rr = f >> 3, ch = f & 7;
    uint4 v = *reinterpret_cast<const uint4*>(Ab + (size_t)rr * 1024 + ch * 8);
    float* dst = &Lt[rr][ch * 8];
    dst[0] = bflo(v.x); dst[1] = bfhi(v.x); dst[2] = bflo(v.y); dst[3] = bfhi(v.y);
    dst[4] = bflo(v.z); dst[5] = bfhi(v.z); dst[6] = bflo(v.w); dst[7] = bfhi(v.w);
  }
  if (tid < 64) sv[tid] = invs[sys * 1024 + k * 64 + tid];
#pragma unroll
  for (int c = 0; c < 16; ++c) W[r][cq * 16 + c] = (r == cq * 16 + c) ? 1.f : 0.f;
  __syncthreads();

  for (int r2 = 0; r2 < 64; ++r2) {
    float dinv = 1.0f / (1.0f + sv[r2] * Lt[r2][r2]);
    if (r == r2) {
#pragma unroll
      for (int c = 0; c < 16; ++c) W[r2][cq * 16 + c] *= dinv;
    }
    __syncthreads();
    if (r > r2) {
      float f = sv[r] * Lt[r][r2];
#pragma unroll
      for (int c = 0; c < 16; ++c) W[r][cq * 16 + c] -= f * W[r2][cq * 16 + c];
    }
    __syncthreads();
  }

#pragma unroll
  for (int m = 0; m < 8; ++m) {
    int f = m * 256 + tid;
    int rr = f >> 5, cp = (f & 31) * 2;
    unsigned pk = (unsigned)bfr(W[rr][cp]) | ((unsigned)bfr(W[rr][cp + 1]) << 16);
    *reinterpret_cast<unsigned*>(Ab + (size_t)rr * 1024 + cp) = pk;
  }
}

// ---------------------------------------------------------------------------
// K3b: right-looking MFMA solve. (unchanged, proven round 11)
// ---------------------------------------------------------------------------
__global__ __launch_bounds__(1024) void solve_mfma_kernel(
    const u16* __restrict__ A, const float* __restrict__ invs,
    const float* __restrict__ Vt, float* __restrict__ Yout) {
  const int sys = blockIdx.x, cq = blockIdx.y;
  const int bb = sys >> 3, kvh = (sys & 7) >> 1;
  const int c0 = cq * 16;
  const int tid = threadIdx.x;
  const int lane = tid & 63, w = tid >> 6;  // 16 waves
  const int ln = lane & 15, kg = lane >> 4;

  const u16* Ab = A + ((size_t)sys << 20);
  const float* Vb = Vt + ((size_t)(bb * KVHN + kvh) * TT) * 64;
  float* Yg = Yout + (size_t)sys * TT * 64;

  __shared__ float U[16][1028];
  __shared__ u16 yh[16 * 64], yl[16 * 64];
  __shared__ u16 uh[16 * 64], ul[16 * 64];

  {
    float* Uf = &U[0][0];
    for (int i = tid; i < 16 * 1028; i += 1024) Uf[i] = 0.f;
  }
  __syncthreads();

  for (int k = 0; k < 16; ++k) {
    const int rg0 = k * 64;

    if (w < 4) {
      const int m0 = w * 16;
      f32x4 u;
#pragma unroll
      for (int j = 0; j < 4; ++j) {
        int gr = rg0 + m0 + kg * 4 + j;
        float si = invs[sys * 1024 + gr];
        u[j] = Vb[(size_t)gr * 64 + c0 + ln] - si * U[ln][gr];
      }
      st_split_lds(uh, ul, ln, m0 + kg * 4, u);
    }
    __syncthreads();

    if (w < 4) {
      const int m0 = w * 16;
      const u16* mrow = Ab + (size_t)(rg0 + m0 + ln) * 1024 + rg0;
      bf16x8 ma0 = ld8_g(mrow + kg * 8);
      bf16x8 ma1 = ld8_g(mrow + 32 + kg * 8);
      f32x4 y = {0.f, 0.f, 0.f, 0.f};
      y = MFMA(ma0, ld8_lds(uh, ln, kg), y);
      y = MFMA(ma1, ld8_lds(uh, ln, 4 + kg), y);
      y = MFMA(ma0, ld8_lds(ul, ln, kg), y);
      y = MFMA(ma1, ld8_lds(ul, ln, 4 + kg), y);
#pragma unroll
      for (int j = 0; j < 4; ++j)
        Yg[(size_t)(rg0 + m0 + kg * 4 + j) * 64 + c0 + ln] = y[j];
      st_split_lds(yh, yl, ln, m0 + kg * 4, y);
    }
    __syncthreads();

    const int nu = (15 - k) * 4;
    for (int un = w; un < nu; un += 16) {
      const int i = k + 1 + (un >> 2), rq = un & 3;
      const u16* arow = Ab + (size_t)(i * 64 + rq * 16 + ln) * 1024 + rg0;
      bf16x8 a0 = ld8_g(arow + kg * 8);
      bf16x8 a1 = ld8_g(arow + 32 + kg * 8);
      f32x4 s = {0.f, 0.f, 0.f, 0.f};
      s = MFMA(a0, ld8_lds(yh, ln, kg), s);
      s = MFMA(a1, ld8_lds(yh, ln, 4 + kg), s);
      s = MFMA(a0, ld8_lds(yl, ln, kg), s);
      s = MFMA(a1, ld8_lds(yl, ln, 4 + kg), s);
      const int rb = i * 64 + rq * 16 + kg * 4;
#pragma unroll
      for (int j = 0; j < 4; ++j) U[ln][rb + j] += s[j];
    }
    __syncthreads();
  }
}

// ---------------------------------------------------------------------------
// K4: out = x + Y2d @ Wo as tiled GEMM. (unchanged, proven)
// ---------------------------------------------------------------------------
__global__ __launch_bounds__(256) void out_proj_kernel(
    const float* __restrict__ Y, const float* __restrict__ x,
    const float* __restrict__ Wo, float* __restrict__ out) {
  const int bx = blockIdx.x, by = blockIdx.y;
  const int tid = threadIdx.x;
  const int ti = tid >> 4, tj = tid & 15;
  const int m0 = bx * 64, n0 = by * 64;

  __shared__ float Ys[64][68];
  __shared__ float Ws[64][68];

  float acc[4][4] = {};

  for (int k0 = 0; k0 < 512; k0 += 64) {
    const int h = k0 >> 6;
    __syncthreads();
#pragma unroll
    for (int m = 0; m < 4; ++m) {
      int f = m * 256 + tid;
      int rr = f >> 4, dc = (f & 15) * 4;
      int row = m0 + rr, b = row >> 10, t = row & 1023;
      *reinterpret_cast<float4*>(&Ys[rr][dc]) =
          *reinterpret_cast<const float4*>(
              Y + ((size_t)(b * HH + h) * TT + t) * 64 + dc);
    }
#pragma unroll
    for (int m = 0; m < 4; ++m) {
      int f = m * 256 + tid;
      int rr = f >> 4, dc = (f & 15) * 4;
      *reinterpret_cast<float4*>(&Ws[rr][dc]) =
          *reinterpret_cast<const float4*>(Wo + (size_t)(k0 + rr) * 512 + n0 + dc);
    }
    __syncthreads();

    for (int d = 0; d < 64; d += 4) {
      float4 wv[4];
#pragma unroll
      for (int dd = 0; dd < 4; ++dd)
        wv[dd] = *reinterpret_cast<const float4*>(&Ws[d + dd][4 * tj]);
#pragma unroll
      for (int i2 = 0; i2 < 4; ++i2) {
        float4 xv = *reinterpret_cast<const float4*>(&Ys[4 * ti + i2][d]);
        acc[i2][0] += xv.x * wv[0].x + xv.y * wv[1].x + xv.z * wv[2].x + xv.w * wv[3].x;
        acc[i2][1] += xv.x * wv[0].y + xv.y * wv[1].y + xv.z * wv[2].y + xv.w * wv[3].y;
        acc[i2][2] += xv.x * wv[0].z + xv.y * wv[1].z + xv.z * wv[2].z + xv.w * wv[3].z;
        acc[i2][3] += xv.x * wv[0].w + xv.y * wv[1].w + xv.z * wv[2].w + xv.w * wv[3].w;
      }
    }
  }

#pragma unroll
  for (int i2 = 0; i2 < 4; ++i2) {
    size_t row = (size_t)(m0 + 4 * ti + i2);
    float4 xr = *reinterpret_cast<const float4*>(x + row * 512 + n0 + 4 * tj);
    float4 v;
    v.x = xr.x + acc[i2][0]; v.y = xr.y + acc[i2][1];
    v.z = xr.z + acc[i2][2]; v.w = xr.w + acc[i2][3];
    *reinterpret_cast<float4*>(out + row * 512 + n0 + 4 * tj) = v;
  }
}

// ---------------------------------------------------------------------------
extern "C" void kernel_launch(void* const* d_in, const int* in_sizes, int n_in,
                              void* d_out, int out_size, void* d_ws,
                              size_t ws_size, hipStream_t stream) {
  (void)in_sizes; (void)n_in; (void)out_size; (void)ws_size;
  const float* x = (const float*)d_in[0];
  const float* cosb = (const float*)d_in[1];
  const float* sinb = (const float*)d_in[2];
  const float* Wq = (const float*)d_in[3];
  const float* Wk = (const float*)d_in[4];
  const float* Wv = (const float*)d_in[5];
  const float* Wo = (const float*)d_in[6];
  float* out = (float*)d_out;

  float* ws = (float*)d_ws;
  float* Q = ws;                        // 1,048,576 f
  float* Kt = Q + (size_t)1048576;      //   524,288 f
  float* Vt = Kt + (size_t)524288;      //   524,288 f
  float* Yb = Vt + (size_t)524288;      // 1,048,576 f
  float* invs = Yb + (size_t)1048576;   //    16,384 f
  float* part = invs + (size_t)16384;   //   262,144 f (16 sys x 16 jt x 1024)
  u16* A = (u16*)(part + 262144);       // 16,777,216 u16 = 32 MB (~45 MB total)

  qkv_kernel<<<dim3(32, 16), 256, 0, stream>>>(x, cosb, sinb, Wq, Wk, Wv, Q, Kt, Vt);
  logits_mfma_kernel<<<dim3(136, 16), 256, 0, stream>>>(Q, Kt, A, part);
  invs_kernel<<<16, 1024, 0, stream>>>(part, invs);
  diaginv_kernel<<<dim3(16, 16), 256, 0, stream>>>(A, invs);
  solve_mfma_kernel<<<dim3(16, 4), 1024, 0, stream>>>(A, invs, Vt, Yb);
  out_proj_kernel<<<dim3(32, 8), 256, 0, stream>>>(Yb, x, Wo, out);
}

// Round 13
// 210.344 us; speedup vs baseline: 1.7797x; 1.1069x over previous
//
#include <hip/hip_runtime.h>
#include <cmath>

#define TT 1024
#define HH 8
#define KVHN 4

typedef unsigned short u16;
typedef __attribute__((ext_vector_type(8))) short bf16x8;
typedef __attribute__((ext_vector_type(4))) float f32x4;

#define MFMA(a, b, c) __builtin_amdgcn_mfma_f32_16x16x32_bf16(a, b, c, 0, 0, 0)

__device__ __forceinline__ float bflo(unsigned u) { return __uint_as_float(u << 16); }
__device__ __forceinline__ float bfhi(unsigned u) { return __uint_as_float(u & 0xffff0000u); }
__device__ __forceinline__ u16 bfr(float f) {
  unsigned u = __float_as_uint(f);
  return (u16)((u + 0x7fffu + ((u >> 16) & 1u)) >> 16);
}

__device__ __forceinline__ bf16x8 ld8_g(const u16* __restrict__ p) {
  uint4 v = *reinterpret_cast<const uint4*>(p);
  return __builtin_bit_cast(bf16x8, v);
}
__device__ __forceinline__ bf16x8 ld8_lds(const u16* s, int col, int k8) {
  const uint4* p = reinterpret_cast<const uint4*>(s);
  return __builtin_bit_cast(bf16x8, p[col * 8 + (k8 ^ (col & 7))]);
}
__device__ __forceinline__ void st_split_lds(u16* sh, u16* sl, int col, int r0,
                                             f32x4 v) {
  u16 hh[4], ll[4];
#pragma unroll
  for (int j = 0; j < 4; ++j) {
    u16 hb = bfr(v[j]);
    hh[j] = hb;
    ll[j] = bfr(v[j] - __uint_as_float((unsigned)hb << 16));
  }
  uint2 ph, pl;
  ph.x = (unsigned)hh[0] | ((unsigned)hh[1] << 16);
  ph.y = (unsigned)hh[2] | ((unsigned)hh[3] << 16);
  pl.x = (unsigned)ll[0] | ((unsigned)ll[1] << 16);
  pl.y = (unsigned)ll[2] | ((unsigned)ll[3] << 16);
  int idx = col * 64 + (((r0 >> 3) ^ (col & 7)) << 3) + (r0 & 7);
  *reinterpret_cast<uint2*>(sh + idx) = ph;
  *reinterpret_cast<uint2*>(sl + idx) = pl;
}
// load 8 consecutive f32 at p, split into hi/lo bf16x8 fragments
__device__ __forceinline__ void cvt8(const float* __restrict__ p, bf16x8& h,
                                     bf16x8& l) {
  float4 a = *reinterpret_cast<const float4*>(p);
  float4 b = *reinterpret_cast<const float4*>(p + 4);
  float v[8] = {a.x, a.y, a.z, a.w, b.x, b.y, b.z, b.w};
  unsigned hh[8], ll[8];
#pragma unroll
  for (int j = 0; j < 8; ++j) {
    u16 hb = bfr(v[j]);
    hh[j] = hb;
    ll[j] = bfr(v[j] - __uint_as_float((unsigned)hb << 16));
  }
  uint4 H, L;
  H.x = hh[0] | (hh[1] << 16); H.y = hh[2] | (hh[3] << 16);
  H.z = hh[4] | (hh[5] << 16); H.w = hh[6] | (hh[7] << 16);
  L.x = ll[0] | (ll[1] << 16); L.y = ll[2] | (ll[3] << 16);
  L.z = ll[4] | (ll[5] << 16); L.w = ll[6] | (ll[7] << 16);
  h = __builtin_bit_cast(bf16x8, H);
  l = __builtin_bit_cast(bf16x8, L);
}

// ---------------------------------------------------------------------------
// K0: prep — transpose+split weights to bf16 hi/lo [n][k]; convert x to hi/lo.
// Grid (8 k-tiles, 56 tiles): nt<16 Wqkv cols, nt<24 Wo cols, else x rows.
// ---------------------------------------------------------------------------
__global__ __launch_bounds__(256) void prep_kernel(
    const float* __restrict__ x, const float* __restrict__ Wq,
    const float* __restrict__ Wk, const float* __restrict__ Wv,
    const float* __restrict__ Wo, u16* __restrict__ WtH, u16* __restrict__ WtL,
    u16* __restrict__ WotH, u16* __restrict__ WotL, u16* __restrict__ Xh,
    u16* __restrict__ Xl) {
  const int kt = blockIdx.x, nt = blockIdx.y;
  const int tid = threadIdx.x;
  const int k0 = kt * 64;

  if (nt >= 24) {
    // x convert (no transpose): rows r0..+63, cols k0..+63
    const int r0 = (nt - 24) * 64;
    const int rr = tid >> 2, kc0 = (tid & 3) * 16;
    const float* src = x + (size_t)(r0 + rr) * 512 + k0 + kc0;
    u16* dh = Xh + (size_t)(r0 + rr) * 512 + k0 + kc0;
    u16* dl = Xl + (size_t)(r0 + rr) * 512 + k0 + kc0;
#pragma unroll
    for (int m = 0; m < 4; ++m) {
      float4 v = *reinterpret_cast<const float4*>(src + m * 4);
      float vv[4] = {v.x, v.y, v.z, v.w};
      u16 hh[4], ll[4];
#pragma unroll
      for (int j = 0; j < 4; ++j) {
        u16 hb = bfr(vv[j]);
        hh[j] = hb;
        ll[j] = bfr(vv[j] - __uint_as_float((unsigned)hb << 16));
      }
      uint2 ph, pl;
      ph.x = (unsigned)hh[0] | ((unsigned)hh[1] << 16);
      ph.y = (unsigned)hh[2] | ((unsigned)hh[3] << 16);
      pl.x = (unsigned)ll[0] | ((unsigned)ll[1] << 16);
      pl.y = (unsigned)ll[2] | ((unsigned)ll[3] << 16);
      *reinterpret_cast<uint2*>(dh + m * 4) = ph;
      *reinterpret_cast<uint2*>(dl + m * 4) = pl;
    }
    return;
  }

  const float* Wsel;
  int wstride, wc0;
  u16 *oh, *ol;
  if (nt < 16) {
    if (nt < 8) { Wsel = Wq; wstride = 512; wc0 = nt * 64; }
    else if (nt < 12) { Wsel = Wk; wstride = 256; wc0 = (nt - 8) * 64; }
    else { Wsel = Wv; wstride = 256; wc0 = (nt - 12) * 64; }
    oh = WtH + (size_t)(nt * 64) * 512;
    ol = WtL + (size_t)(nt * 64) * 512;
  } else {
    Wsel = Wo; wstride = 512; wc0 = (nt - 16) * 64;
    oh = WotH + (size_t)((nt - 16) * 64) * 512;
    ol = WotL + (size_t)((nt - 16) * 64) * 512;
  }

  __shared__ float Ws[64][68];
#pragma unroll
  for (int m = 0; m < 4; ++m) {
    int f = m * 256 + tid;
    int rr = f >> 4, dc = (f & 15) * 4;
    *reinterpret_cast<float4*>(&Ws[rr][dc]) =
        *reinterpret_cast<const float4*>(Wsel + (size_t)(k0 + rr) * wstride + wc0 + dc);
  }
  __syncthreads();

  const int nr = tid >> 2, kc0 = (tid & 3) * 16;
  u16* dh = oh + (size_t)nr * 512 + k0 + kc0;
  u16* dl = ol + (size_t)nr * 512 + k0 + kc0;
#pragma unroll
  for (int i = 0; i < 16; i += 2) {
    float a = Ws[kc0 + i][nr], b = Ws[kc0 + i + 1][nr];
    u16 ha = bfr(a), hb2 = bfr(b);
    u16 la = bfr(a - __uint_as_float((unsigned)ha << 16));
    u16 lb = bfr(b - __uint_as_float((unsigned)hb2 << 16));
    *reinterpret_cast<unsigned*>(dh + i) = (unsigned)ha | ((unsigned)hb2 << 16);
    *reinterpret_cast<unsigned*>(dl + i) = (unsigned)la | ((unsigned)lb << 16);
  }
}

// ---------------------------------------------------------------------------
// K1: QKV projection via MFMA (hi/lo split) + fused RoPE epilogue.
// Grid (32 row-tiles, 16 col-tiles), 256 thr (4 waves, 16 rows x 64 cols each).
// ---------------------------------------------------------------------------
__global__ __launch_bounds__(256) void qkv_mfma_kernel(
    const u16* __restrict__ Xh, const u16* __restrict__ Xl,
    const u16* __restrict__ WtH, const u16* __restrict__ WtL,
    const float* __restrict__ cosb, const float* __restrict__ sinb,
    float* __restrict__ Q, float* __restrict__ Kt, float* __restrict__ Vt) {
  const int bx = blockIdx.x, cy = blockIdx.y;
  const int tid = threadIdx.x;
  const int lane = tid & 63, w = tid >> 6;
  const int ln = lane & 15, kg = lane >> 4;
  const int n0 = cy * 64;

  const u16* xh = Xh + (size_t)(bx * 64 + w * 16 + ln) * 512 + kg * 8;
  const u16* xl = Xl + (size_t)(bx * 64 + w * 16 + ln) * 512 + kg * 8;
  const u16* wh0 = WtH + (size_t)(n0 + ln) * 512 + kg * 8;
  const u16* wl0 = WtL + (size_t)(n0 + ln) * 512 + kg * 8;

  f32x4 acc[4];
#pragma unroll
  for (int ct = 0; ct < 4; ++ct) acc[ct] = {0.f, 0.f, 0.f, 0.f};

  for (int kk = 0; kk < 16; ++kk) {
    const int k0 = kk * 32;
    bf16x8 ah = ld8_g(xh + k0);
    bf16x8 al = ld8_g(xl + k0);
#pragma unroll
    for (int ct = 0; ct < 4; ++ct) {
      bf16x8 bh = ld8_g(wh0 + (size_t)(ct * 16) * 512 + k0);
      bf16x8 bl = ld8_g(wl0 + (size_t)(ct * 16) * 512 + k0);
      acc[ct] = MFMA(ah, bh, acc[ct]);
      acc[ct] = MFMA(al, bh, acc[ct]);
      acc[ct] = MFMA(ah, bl, acc[ct]);
    }
  }

  __shared__ float Xs[64][68];
#pragma unroll
  for (int ct = 0; ct < 4; ++ct)
#pragma unroll
    for (int j = 0; j < 4; ++j) Xs[w * 16 + kg * 4 + j][ct * 16 + ln] = acc[ct][j];
  __syncthreads();

#pragma unroll
  for (int m = 0; m < 16; ++m) {
    int f = m * 256 + tid;
    int rr = f >> 6, d = f & 63;
    int row = bx * 64 + rr, b = row >> 10, t = row & 1023;
    float val;
    if (cy < 12) {
      int dd = d & 31;
      float c = cosb[t * 32 + dd], s = sinb[t * 32 + dd];
      float v1 = Xs[rr][dd], v2 = Xs[rr][dd + 32];
      val = (d < 32) ? (v1 * c + v2 * s) : (v2 * c - v1 * s);
    } else {
      val = Xs[rr][d];
    }
    if (cy < 8)
      Q[((size_t)(b * HH + cy) * TT + t) * 64 + d] = val;
    else if (cy < 12)
      Kt[((size_t)(b * KVHN + cy - 8) * TT + t) * 64 + d] = val;
    else
      Vt[((size_t)(b * KVHN + cy - 12) * TT + t) * 64 + d] = val;
  }
}

// ---------------------------------------------------------------------------
// K2a: MFMA causal logits + exp (UNNORMALIZED) -> A (bf16). (unchanged r12)
// ---------------------------------------------------------------------------
__global__ __launch_bounds__(256) void logits_mfma_kernel(
    const float* __restrict__ Q, const float* __restrict__ Kt,
    u16* __restrict__ A, float* __restrict__ part) {
  const int n = blockIdx.x, sys = blockIdx.y;
  int it = 0;
  while ((it + 1) * (it + 2) / 2 <= n) ++it;
  const int jt = n - it * (it + 1) / 2;
  const int b = sys >> 3, kvh = (sys & 7) >> 1;
  const int tid = threadIdx.x;
  const int lane = tid & 63, w = tid >> 6;
  const int ln = lane & 15, kg = lane >> 4;
  const int m0 = w * 16;

  const float* Qr = Q + ((size_t)sys * TT + it * 64 + m0 + ln) * 64;
  const float* Kb = Kt + ((size_t)(b * KVHN + kvh) * TT + jt * 64) * 64;
  u16* Aout = A + ((size_t)sys << 20);

  bf16x8 qh0, ql0, qh1, ql1;
  cvt8(Qr + kg * 8, qh0, ql0);
  cvt8(Qr + 32 + kg * 8, qh1, ql1);

  f32x4 acc[4];
#pragma unroll
  for (int ct = 0; ct < 4; ++ct) {
    const float* Kr = Kb + (size_t)(ct * 16 + ln) * 64;
    bf16x8 kh0, kl0, kh1, kl1;
    cvt8(Kr + kg * 8, kh0, kl0);
    cvt8(Kr + 32 + kg * 8, kh1, kl1);
    f32x4 a = {0.f, 0.f, 0.f, 0.f};
    a = MFMA(qh0, kh0, a);
    a = MFMA(qh1, kh1, a);
    a = MFMA(qh0, kl0, a);
    a = MFMA(qh1, kl1, a);
    a = MFMA(ql0, kh0, a);
    a = MFMA(ql1, kh1, a);
    acc[ct] = a;
  }

  const int grow0 = it * 64 + m0;
  const bool full = (jt < it);
  float s[4] = {0.f, 0.f, 0.f, 0.f};
#pragma unroll
  for (int ct = 0; ct < 4; ++ct) {
    int col = jt * 64 + ct * 16 + ln;
#pragma unroll
    for (int j = 0; j < 4; ++j) {
      int row = grow0 + kg * 4 + j;
      float e = (full || col <= row) ? __expf(acc[ct][j] * 0.125f) : 0.f;
      s[j] += e;
      Aout[(size_t)row * 1024 + col] = bfr(e);
    }
  }

#pragma unroll
  for (int off = 1; off < 16; off <<= 1) {
#pragma unroll
    for (int j = 0; j < 4; ++j) s[j] += __shfl_xor(s[j], off);
  }
  if (ln == 0) {
#pragma unroll
    for (int j = 0; j < 4; ++j)
      part[((size_t)(sys * 16 + jt)) * 1024 + grow0 + kg * 4 + j] = s[j];
  }
}

// ---------------------------------------------------------------------------
// K2b: invs[row] = 1 / sum_jt part. (unchanged)
// ---------------------------------------------------------------------------
__global__ __launch_bounds__(1024) void invs_kernel(
    const float* __restrict__ part, float* __restrict__ invs) {
  const int sys = blockIdx.x, r = threadIdx.x;
  const int itop = r >> 6;
  float s = 0.f;
  for (int jt = 0; jt <= itop; ++jt)
    s += part[((size_t)(sys * 16 + jt)) * 1024 + r];
  invs[sys * 1024 + r] = 1.0f / s;
}

// ---------------------------------------------------------------------------
// K3a: invert each (I + S*L_kk) diagonal block IN PLACE over bf16 A. (unchanged)
// ---------------------------------------------------------------------------
__global__ __launch_bounds__(256) void diaginv_kernel(
    u16* __restrict__ A, const float* __restrict__ invs) {
  const int k = blockIdx.x, sys = blockIdx.y;
  const int tid = threadIdx.x;
  const int r = tid & 63, cq = tid >> 6;

  u16* Ab = A + ((size_t)sys << 20) + (size_t)(k * 64) * 1024 + k * 64;

  __shared__ float Lt[64][65];
  __shared__ float W[64][65];
  __shared__ float sv[64];

#pragma unroll
  for (int m = 0; m < 2; ++m) {
    int f = m * 256 + tid;
    int rr = f >> 3, ch = f & 7;
    uint4 v = *reinterpret_cast<const uint4*>(Ab + (size_t)rr * 1024 + ch * 8);
    float* dst = &Lt[rr][ch * 8];
    dst[0] = bflo(v.x); dst[1] = bfhi(v.x); dst[2] = bflo(v.y); dst[3] = bfhi(v.y);
    dst[4] = bflo(v.z); dst[5] = bfhi(v.z); dst[6] = bflo(v.w); dst[7] = bfhi(v.w);
  }
  if (tid < 64) sv[tid] = invs[sys * 1024 + k * 64 + tid];
#pragma unroll
  for (int c = 0; c < 16; ++c) W[r][cq * 16 + c] = (r == cq * 16 + c) ? 1.f : 0.f;
  __syncthreads();

  for (int r2 = 0; r2 < 64; ++r2) {
    float dinv = 1.0f / (1.0f + sv[r2] * Lt[r2][r2]);
    if (r == r2) {
#pragma unroll
      for (int c = 0; c < 16; ++c) W[r2][cq * 16 + c] *= dinv;
    }
    __syncthreads();
    if (r > r2) {
      float f = sv[r] * Lt[r][r2];
#pragma unroll
      for (int c = 0; c < 16; ++c) W[r][cq * 16 + c] -= f * W[r2][cq * 16 + c];
    }
    __syncthreads();
  }

#pragma unroll
  for (int m = 0; m < 8; ++m) {
    int f = m * 256 + tid;
    int rr = f >> 5, cp = (f & 31) * 2;
    unsigned pk = (unsigned)bfr(W[rr][cp]) | ((unsigned)bfr(W[rr][cp + 1]) << 16);
    *reinterpret_cast<unsigned*>(Ab + (size_t)rr * 1024 + cp) = pk;
  }
}

// ---------------------------------------------------------------------------
// K3b: right-looking MFMA solve. (unchanged, proven round 11)
// ---------------------------------------------------------------------------
__global__ __launch_bounds__(1024) void solve_mfma_kernel(
    const u16* __restrict__ A, const float* __restrict__ invs,
    const float* __restrict__ Vt, float* __restrict__ Yout) {
  const int sys = blockIdx.x, cq = blockIdx.y;
  const int bb = sys >> 3, kvh = (sys & 7) >> 1;
  const int c0 = cq * 16;
  const int tid = threadIdx.x;
  const int lane = tid & 63, w = tid >> 6;
  const int ln = lane & 15, kg = lane >> 4;

  const u16* Ab = A + ((size_t)sys << 20);
  const float* Vb = Vt + ((size_t)(bb * KVHN + kvh) * TT) * 64;
  float* Yg = Yout + (size_t)sys * TT * 64;

  __shared__ float U[16][1028];
  __shared__ u16 yh[16 * 64], yl[16 * 64];
  __shared__ u16 uh[16 * 64], ul[16 * 64];

  {
    float* Uf = &U[0][0];
    for (int i = tid; i < 16 * 1028; i += 1024) Uf[i] = 0.f;
  }
  __syncthreads();

  for (int k = 0; k < 16; ++k) {
    const int rg0 = k * 64;

    if (w < 4) {
      const int m0 = w * 16;
      f32x4 u;
#pragma unroll
      for (int j = 0; j < 4; ++j) {
        int gr = rg0 + m0 + kg * 4 + j;
        float si = invs[sys * 1024 + gr];
        u[j] = Vb[(size_t)gr * 64 + c0 + ln] - si * U[ln][gr];
      }
      st_split_lds(uh, ul, ln, m0 + kg * 4, u);
    }
    __syncthreads();

    if (w < 4) {
      const int m0 = w * 16;
      const u16* mrow = Ab + (size_t)(rg0 + m0 + ln) * 1024 + rg0;
      bf16x8 ma0 = ld8_g(mrow + kg * 8);
      bf16x8 ma1 = ld8_g(mrow + 32 + kg * 8);
      f32x4 y = {0.f, 0.f, 0.f, 0.f};
      y = MFMA(ma0, ld8_lds(uh, ln, kg), y);
      y = MFMA(ma1, ld8_lds(uh, ln, 4 + kg), y);
      y = MFMA(ma0, ld8_lds(ul, ln, kg), y);
      y = MFMA(ma1, ld8_lds(ul, ln, 4 + kg), y);
#pragma unroll
      for (int j = 0; j < 4; ++j)
        Yg[(size_t)(rg0 + m0 + kg * 4 + j) * 64 + c0 + ln] = y[j];
      st_split_lds(yh, yl, ln, m0 + kg * 4, y);
    }
    __syncthreads();

    const int nu = (15 - k) * 4;
    for (int un = w; un < nu; un += 16) {
      const int i = k + 1 + (un >> 2), rq = un & 3;
      const u16* arow = Ab + (size_t)(i * 64 + rq * 16 + ln) * 1024 + rg0;
      bf16x8 a0 = ld8_g(arow + kg * 8);
      bf16x8 a1 = ld8_g(arow + 32 + kg * 8);
      f32x4 s = {0.f, 0.f, 0.f, 0.f};
      s = MFMA(a0, ld8_lds(yh, ln, kg), s);
      s = MFMA(a1, ld8_lds(yh, ln, 4 + kg), s);
      s = MFMA(a0, ld8_lds(yl, ln, kg), s);
      s = MFMA(a1, ld8_lds(yl, ln, 4 + kg), s);
      const int rb = i * 64 + rq * 16 + kg * 4;
#pragma unroll
      for (int j = 0; j < 4; ++j) U[ln][rb + j] += s[j];
    }
    __syncthreads();
  }
}

// ---------------------------------------------------------------------------
// K4: out = x + Y2d @ Wo via MFMA (hi/lo). Grid (32, 8), 256 thr (4 waves).
// A-frags cvt8'd on the fly from f32 Y; B from pre-transposed WotH/L.
// ---------------------------------------------------------------------------
__global__ __launch_bounds__(256) void out_proj_mfma_kernel(
    const float* __restrict__ Y, const u16* __restrict__ WotH,
    const u16* __restrict__ WotL, const float* __restrict__ x,
    float* __restrict__ out) {
  const int bx = blockIdx.x, by = blockIdx.y;
  const int tid = threadIdx.x;
  const int lane = tid & 63, w = tid >> 6;
  const int ln = lane & 15, kg = lane >> 4;
  const int n0 = by * 64;
  const int m = bx * 64 + w * 16 + ln;  // A-frag row
  const int b = m >> 10, t = m & 1023;

  const u16* wh0 = WotH + (size_t)(n0 + ln) * 512 + kg * 8;
  const u16* wl0 = WotL + (size_t)(n0 + ln) * 512 + kg * 8;

  f32x4 acc[4];
#pragma unroll
  for (int ct = 0; ct < 4; ++ct) acc[ct] = {0.f, 0.f, 0.f, 0.f};

  for (int kk = 0; kk < 16; ++kk) {
    const int k0 = kk * 32;
    const int h = k0 >> 6, d0 = (k0 & 63) + kg * 8;
    bf16x8 ah, al;
    cvt8(Y + ((size_t)(b * HH + h) * TT + t) * 64 + d0, ah, al);
#pragma unroll
    for (int ct = 0; ct < 4; ++ct) {
      bf16x8 bh = ld8_g(wh0 + (size_t)(ct * 16) * 512 + k0);
      bf16x8 bl = ld8_g(wl0 + (size_t)(ct * 16) * 512 + k0);
      acc[ct] = MFMA(ah, bh, acc[ct]);
      acc[ct] = MFMA(al, bh, acc[ct]);
      acc[ct] = MFMA(ah, bl, acc[ct]);
    }
  }

#pragma unroll
  for (int ct = 0; ct < 4; ++ct) {
#pragma unroll
    for (int j = 0; j < 4; ++j) {
      size_t row = (size_t)(bx * 64 + w * 16 + kg * 4 + j);
      int col = n0 + ct * 16 + ln;
      out[row * 512 + col] = x[row * 512 + col] + acc[ct][j];
    }
  }
}

// ---------------------------------------------------------------------------
extern "C" void kernel_launch(void* const* d_in, const int* in_sizes, int n_in,
                              void* d_out, int out_size, void* d_ws,
                              size_t ws_size, hipStream_t stream) {
  (void)in_sizes; (void)n_in; (void)out_size; (void)ws_size;
  const float* x = (const float*)d_in[0];
  const float* cosb = (const float*)d_in[1];
  const float* sinb = (const float*)d_in[2];
  const float* Wq = (const float*)d_in[3];
  const float* Wk = (const float*)d_in[4];
  const float* Wv = (const float*)d_in[5];
  const float* Wo = (const float*)d_in[6];
  float* out = (float*)d_out;

  float* ws = (float*)d_ws;
  float* Q = ws;                        // 1,048,576 f
  float* Kt = Q + (size_t)1048576;      //   524,288 f
  float* Vt = Kt + (size_t)524288;      //   524,288 f
  float* Yb = Vt + (size_t)524288;      // 1,048,576 f
  float* invs = Yb + (size_t)1048576;   //    16,384 f
  float* part = invs + (size_t)16384;   //   262,144 f
  u16* A = (u16*)(part + 262144);       // 16,777,216 u16 = 32 MB
  u16* WtH = A + (size_t)16777216;      //   524,288 u16 (1024x512)
  u16* WtL = WtH + (size_t)524288;
  u16* WotH = WtL + (size_t)524288;     //   262,144 u16 (512x512)
  u16* WotL = WotH + (size_t)262144;
  u16* Xh = WotL + (size_t)262144;      // 1,048,576 u16 (2048x512)
  u16* Xl = Xh + (size_t)1048576;       // total ~55 MB

  prep_kernel<<<dim3(8, 56), 256, 0, stream>>>(x, Wq, Wk, Wv, Wo, WtH, WtL,
                                               WotH, WotL, Xh, Xl);
  qkv_mfma_kernel<<<dim3(32, 16), 256, 0, stream>>>(Xh, Xl, WtH, WtL, cosb,
                                                    sinb, Q, Kt, Vt);
  logits_mfma_kernel<<<dim3(136, 16), 256, 0, stream>>>(Q, Kt, A, part);
  invs_kernel<<<16, 1024, 0, stream>>>(part, invs);
  diaginv_kernel<<<dim3(16, 16), 256, 0, stream>>>(A, invs);
  solve_mfma_kernel<<<dim3(16, 4), 1024, 0, stream>>>(A, invs, Vt, Yb);
  out_proj_mfma_kernel<<<dim3(32, 8), 256, 0, stream>>>(Yb, WotH, WotL, x, out);
}

// Round 14
// 200.323 us; speedup vs baseline: 1.8687x; 1.0500x over previous
//
#include <hip/hip_runtime.h>
#include <cmath>

#define TT 1024
#define HH 8
#define KVHN 4

typedef unsigned short u16;
typedef __attribute__((ext_vector_type(8))) short bf16x8;
typedef __attribute__((ext_vector_type(4))) float f32x4;

#define MFMA(a, b, c) __builtin_amdgcn_mfma_f32_16x16x32_bf16(a, b, c, 0, 0, 0)

__device__ __forceinline__ float bflo(unsigned u) { return __uint_as_float(u << 16); }
__device__ __forceinline__ float bfhi(unsigned u) { return __uint_as_float(u & 0xffff0000u); }
__device__ __forceinline__ u16 bfr(float f) {
  unsigned u = __float_as_uint(f);
  return (u16)((u + 0x7fffu + ((u >> 16) & 1u)) >> 16);
}

__device__ __forceinline__ bf16x8 ld8_g(const u16* __restrict__ p) {
  uint4 v = *reinterpret_cast<const uint4*>(p);
  return __builtin_bit_cast(bf16x8, v);
}
__device__ __forceinline__ bf16x8 ld8_lds(const u16* s, int col, int k8) {
  const uint4* p = reinterpret_cast<const uint4*>(s);
  return __builtin_bit_cast(bf16x8, p[col * 8 + (k8 ^ (col & 7))]);
}
__device__ __forceinline__ void st_split_lds(u16* sh, u16* sl, int col, int r0,
                                             f32x4 v) {
  u16 hh[4], ll[4];
#pragma unroll
  for (int j = 0; j < 4; ++j) {
    u16 hb = bfr(v[j]);
    hh[j] = hb;
    ll[j] = bfr(v[j] - __uint_as_float((unsigned)hb << 16));
  }
  uint2 ph, pl;
  ph.x = (unsigned)hh[0] | ((unsigned)hh[1] << 16);
  ph.y = (unsigned)hh[2] | ((unsigned)hh[3] << 16);
  pl.x = (unsigned)ll[0] | ((unsigned)ll[1] << 16);
  pl.y = (unsigned)ll[2] | ((unsigned)ll[3] << 16);
  int idx = col * 64 + (((r0 >> 3) ^ (col & 7)) << 3) + (r0 & 7);
  *reinterpret_cast<uint2*>(sh + idx) = ph;
  *reinterpret_cast<uint2*>(sl + idx) = pl;
}
// load 8 consecutive f32 at p, split into hi/lo bf16x8 fragments
__device__ __forceinline__ void cvt8(const float* __restrict__ p, bf16x8& h,
                                     bf16x8& l) {
  float4 a = *reinterpret_cast<const float4*>(p);
  float4 b = *reinterpret_cast<const float4*>(p + 4);
  float v[8] = {a.x, a.y, a.z, a.w, b.x, b.y, b.z, b.w};
  unsigned hh[8], ll[8];
#pragma unroll
  for (int j = 0; j < 8; ++j) {
    u16 hb = bfr(v[j]);
    hh[j] = hb;
    ll[j] = bfr(v[j] - __uint_as_float((unsigned)hb << 16));
  }
  uint4 H, L;
  H.x = hh[0] | (hh[1] << 16); H.y = hh[2] | (hh[3] << 16);
  H.z = hh[4] | (hh[5] << 16); H.w = hh[6] | (hh[7] << 16);
  L.x = ll[0] | (ll[1] << 16); L.y = ll[2] | (ll[3] << 16);
  L.z = ll[4] | (ll[5] << 16); L.w = ll[6] | (ll[7] << 16);
  h = __builtin_bit_cast(bf16x8, H);
  l = __builtin_bit_cast(bf16x8, L);
}

// ---------------------------------------------------------------------------
// K0: prep — transpose+split weights to bf16 hi/lo [n][k]; convert x to hi/lo.
// (unchanged, proven round 13)
// ---------------------------------------------------------------------------
__global__ __launch_bounds__(256) void prep_kernel(
    const float* __restrict__ x, const float* __restrict__ Wq,
    const float* __restrict__ Wk, const float* __restrict__ Wv,
    const float* __restrict__ Wo, u16* __restrict__ WtH, u16* __restrict__ WtL,
    u16* __restrict__ WotH, u16* __restrict__ WotL, u16* __restrict__ Xh,
    u16* __restrict__ Xl) {
  const int kt = blockIdx.x, nt = blockIdx.y;
  const int tid = threadIdx.x;
  const int k0 = kt * 64;

  if (nt >= 24) {
    const int r0 = (nt - 24) * 64;
    const int rr = tid >> 2, kc0 = (tid & 3) * 16;
    const float* src = x + (size_t)(r0 + rr) * 512 + k0 + kc0;
    u16* dh = Xh + (size_t)(r0 + rr) * 512 + k0 + kc0;
    u16* dl = Xl + (size_t)(r0 + rr) * 512 + k0 + kc0;
#pragma unroll
    for (int m = 0; m < 4; ++m) {
      float4 v = *reinterpret_cast<const float4*>(src + m * 4);
      float vv[4] = {v.x, v.y, v.z, v.w};
      u16 hh[4], ll[4];
#pragma unroll
      for (int j = 0; j < 4; ++j) {
        u16 hb = bfr(vv[j]);
        hh[j] = hb;
        ll[j] = bfr(vv[j] - __uint_as_float((unsigned)hb << 16));
      }
      uint2 ph, pl;
      ph.x = (unsigned)hh[0] | ((unsigned)hh[1] << 16);
      ph.y = (unsigned)hh[2] | ((unsigned)hh[3] << 16);
      pl.x = (unsigned)ll[0] | ((unsigned)ll[1] << 16);
      pl.y = (unsigned)ll[2] | ((unsigned)ll[3] << 16);
      *reinterpret_cast<uint2*>(dh + m * 4) = ph;
      *reinterpret_cast<uint2*>(dl + m * 4) = pl;
    }
    return;
  }

  const float* Wsel;
  int wstride, wc0;
  u16 *oh, *ol;
  if (nt < 16) {
    if (nt < 8) { Wsel = Wq; wstride = 512; wc0 = nt * 64; }
    else if (nt < 12) { Wsel = Wk; wstride = 256; wc0 = (nt - 8) * 64; }
    else { Wsel = Wv; wstride = 256; wc0 = (nt - 12) * 64; }
    oh = WtH + (size_t)(nt * 64) * 512;
    ol = WtL + (size_t)(nt * 64) * 512;
  } else {
    Wsel = Wo; wstride = 512; wc0 = (nt - 16) * 64;
    oh = WotH + (size_t)((nt - 16) * 64) * 512;
    ol = WotL + (size_t)((nt - 16) * 64) * 512;
  }

  __shared__ float Ws[64][68];
#pragma unroll
  for (int m = 0; m < 4; ++m) {
    int f = m * 256 + tid;
    int rr = f >> 4, dc = (f & 15) * 4;
    *reinterpret_cast<float4*>(&Ws[rr][dc]) =
        *reinterpret_cast<const float4*>(Wsel + (size_t)(k0 + rr) * wstride + wc0 + dc);
  }
  __syncthreads();

  const int nr = tid >> 2, kc0 = (tid & 3) * 16;
  u16* dh = oh + (size_t)nr * 512 + k0 + kc0;
  u16* dl = ol + (size_t)nr * 512 + k0 + kc0;
#pragma unroll
  for (int i = 0; i < 16; i += 2) {
    float a = Ws[kc0 + i][nr], b = Ws[kc0 + i + 1][nr];
    u16 ha = bfr(a), hb2 = bfr(b);
    u16 la = bfr(a - __uint_as_float((unsigned)ha << 16));
    u16 lb = bfr(b - __uint_as_float((unsigned)hb2 << 16));
    *reinterpret_cast<unsigned*>(dh + i) = (unsigned)ha | ((unsigned)hb2 << 16);
    *reinterpret_cast<unsigned*>(dl + i) = (unsigned)la | ((unsigned)lb << 16);
  }
}

// ---------------------------------------------------------------------------
// K1: QKV projection via MFMA (hi/lo split) + fused RoPE. (unchanged r13)
// ---------------------------------------------------------------------------
__global__ __launch_bounds__(256) void qkv_mfma_kernel(
    const u16* __restrict__ Xh, const u16* __restrict__ Xl,
    const u16* __restrict__ WtH, const u16* __restrict__ WtL,
    const float* __restrict__ cosb, const float* __restrict__ sinb,
    float* __restrict__ Q, float* __restrict__ Kt, float* __restrict__ Vt) {
  const int bx = blockIdx.x, cy = blockIdx.y;
  const int tid = threadIdx.x;
  const int lane = tid & 63, w = tid >> 6;
  const int ln = lane & 15, kg = lane >> 4;
  const int n0 = cy * 64;

  const u16* xh = Xh + (size_t)(bx * 64 + w * 16 + ln) * 512 + kg * 8;
  const u16* xl = Xl + (size_t)(bx * 64 + w * 16 + ln) * 512 + kg * 8;
  const u16* wh0 = WtH + (size_t)(n0 + ln) * 512 + kg * 8;
  const u16* wl0 = WtL + (size_t)(n0 + ln) * 512 + kg * 8;

  f32x4 acc[4];
#pragma unroll
  for (int ct = 0; ct < 4; ++ct) acc[ct] = {0.f, 0.f, 0.f, 0.f};

  for (int kk = 0; kk < 16; ++kk) {
    const int k0 = kk * 32;
    bf16x8 ah = ld8_g(xh + k0);
    bf16x8 al = ld8_g(xl + k0);
#pragma unroll
    for (int ct = 0; ct < 4; ++ct) {
      bf16x8 bh = ld8_g(wh0 + (size_t)(ct * 16) * 512 + k0);
      bf16x8 bl = ld8_g(wl0 + (size_t)(ct * 16) * 512 + k0);
      acc[ct] = MFMA(ah, bh, acc[ct]);
      acc[ct] = MFMA(al, bh, acc[ct]);
      acc[ct] = MFMA(ah, bl, acc[ct]);
    }
  }

  __shared__ float Xs[64][68];
#pragma unroll
  for (int ct = 0; ct < 4; ++ct)
#pragma unroll
    for (int j = 0; j < 4; ++j) Xs[w * 16 + kg * 4 + j][ct * 16 + ln] = acc[ct][j];
  __syncthreads();

#pragma unroll
  for (int m = 0; m < 16; ++m) {
    int f = m * 256 + tid;
    int rr = f >> 6, d = f & 63;
    int row = bx * 64 + rr, b = row >> 10, t = row & 1023;
    float val;
    if (cy < 12) {
      int dd = d & 31;
      float c = cosb[t * 32 + dd], s = sinb[t * 32 + dd];
      float v1 = Xs[rr][dd], v2 = Xs[rr][dd + 32];
      val = (d < 32) ? (v1 * c + v2 * s) : (v2 * c - v1 * s);
    } else {
      val = Xs[rr][d];
    }
    if (cy < 8)
      Q[((size_t)(b * HH + cy) * TT + t) * 64 + d] = val;
    else if (cy < 12)
      Kt[((size_t)(b * KVHN + cy - 8) * TT + t) * 64 + d] = val;
    else
      Vt[((size_t)(b * KVHN + cy - 12) * TT + t) * 64 + d] = val;
  }
}

// ---------------------------------------------------------------------------
// K2: MFMA causal logits + exp (UNNORMALIZED) -> A (bf16). (unchanged r12)
// ---------------------------------------------------------------------------
__global__ __launch_bounds__(256) void logits_mfma_kernel(
    const float* __restrict__ Q, const float* __restrict__ Kt,
    u16* __restrict__ A, float* __restrict__ part) {
  const int n = blockIdx.x, sys = blockIdx.y;
  int it = 0;
  while ((it + 1) * (it + 2) / 2 <= n) ++it;
  const int jt = n - it * (it + 1) / 2;
  const int b = sys >> 3, kvh = (sys & 7) >> 1;
  const int tid = threadIdx.x;
  const int lane = tid & 63, w = tid >> 6;
  const int ln = lane & 15, kg = lane >> 4;
  const int m0 = w * 16;

  const float* Qr = Q + ((size_t)sys * TT + it * 64 + m0 + ln) * 64;
  const float* Kb = Kt + ((size_t)(b * KVHN + kvh) * TT + jt * 64) * 64;
  u16* Aout = A + ((size_t)sys << 20);

  bf16x8 qh0, ql0, qh1, ql1;
  cvt8(Qr + kg * 8, qh0, ql0);
  cvt8(Qr + 32 + kg * 8, qh1, ql1);

  f32x4 acc[4];
#pragma unroll
  for (int ct = 0; ct < 4; ++ct) {
    const float* Kr = Kb + (size_t)(ct * 16 + ln) * 64;
    bf16x8 kh0, kl0, kh1, kl1;
    cvt8(Kr + kg * 8, kh0, kl0);
    cvt8(Kr + 32 + kg * 8, kh1, kl1);
    f32x4 a = {0.f, 0.f, 0.f, 0.f};
    a = MFMA(qh0, kh0, a);
    a = MFMA(qh1, kh1, a);
    a = MFMA(qh0, kl0, a);
    a = MFMA(qh1, kl1, a);
    a = MFMA(ql0, kh0, a);
    a = MFMA(ql1, kh1, a);
    acc[ct] = a;
  }

  const int grow0 = it * 64 + m0;
  const bool full = (jt < it);
  float s[4] = {0.f, 0.f, 0.f, 0.f};
#pragma unroll
  for (int ct = 0; ct < 4; ++ct) {
    int col = jt * 64 + ct * 16 + ln;
#pragma unroll
    for (int j = 0; j < 4; ++j) {
      int row = grow0 + kg * 4 + j;
      float e = (full || col <= row) ? __expf(acc[ct][j] * 0.125f) : 0.f;
      s[j] += e;
      Aout[(size_t)row * 1024 + col] = bfr(e);
    }
  }

#pragma unroll
  for (int off = 1; off < 16; off <<= 1) {
#pragma unroll
    for (int j = 0; j < 4; ++j) s[j] += __shfl_xor(s[j], off);
  }
  if (ln == 0) {
#pragma unroll
    for (int j = 0; j < 4; ++j)
      part[((size_t)(sys * 16 + jt)) * 1024 + grow0 + kg * 4 + j] = s[j];
  }
}

// ---------------------------------------------------------------------------
// K3a: diag-block inversion IN PLACE; now also computes invs = 1/rowsum from
// part (fuses former invs_kernel; one fewer dispatch).
// ---------------------------------------------------------------------------
__global__ __launch_bounds__(256) void diaginv_kernel(
    u16* __restrict__ A, const float* __restrict__ part,
    float* __restrict__ invs) {
  const int k = blockIdx.x, sys = blockIdx.y;
  const int tid = threadIdx.x;
  const int r = tid & 63, cq = tid >> 6;

  u16* Ab = A + ((size_t)sys << 20) + (size_t)(k * 64) * 1024 + k * 64;

  __shared__ float Lt[64][65];
  __shared__ float W[64][65];
  __shared__ float sv[64];

#pragma unroll
  for (int m = 0; m < 2; ++m) {
    int f = m * 256 + tid;
    int rr = f >> 3, ch = f & 7;
    uint4 v = *reinterpret_cast<const uint4*>(Ab + (size_t)rr * 1024 + ch * 8);
    float* dst = &Lt[rr][ch * 8];
    dst[0] = bflo(v.x); dst[1] = bfhi(v.x); dst[2] = bflo(v.y); dst[3] = bfhi(v.y);
    dst[4] = bflo(v.z); dst[5] = bfhi(v.z); dst[6] = bflo(v.w); dst[7] = bfhi(v.w);
  }
  if (tid < 64) {
    float s = 0.f;
    for (int jt = 0; jt <= k; ++jt)
      s += part[((size_t)(sys * 16 + jt)) * 1024 + k * 64 + tid];
    float si = 1.0f / s;
    sv[tid] = si;
    invs[sys * 1024 + k * 64 + tid] = si;
  }
#pragma unroll
  for (int c = 0; c < 16; ++c) W[r][cq * 16 + c] = (r == cq * 16 + c) ? 1.f : 0.f;
  __syncthreads();

  for (int r2 = 0; r2 < 64; ++r2) {
    float dinv = 1.0f / (1.0f + sv[r2] * Lt[r2][r2]);
    if (r == r2) {
#pragma unroll
      for (int c = 0; c < 16; ++c) W[r2][cq * 16 + c] *= dinv;
    }
    __syncthreads();
    if (r > r2) {
      float f = sv[r] * Lt[r][r2];
#pragma unroll
      for (int c = 0; c < 16; ++c) W[r][cq * 16 + c] -= f * W[r2][cq * 16 + c];
    }
    __syncthreads();
  }

#pragma unroll
  for (int m = 0; m < 8; ++m) {
    int f = m * 256 + tid;
    int rr = f >> 5, cp = (f & 31) * 2;
    unsigned pk = (unsigned)bfr(W[rr][cp]) | ((unsigned)bfr(W[rr][cp + 1]) << 16);
    *reinterpret_cast<unsigned*>(Ab + (size_t)rr * 1024 + cp) = pk;
  }
}

// ---------------------------------------------------------------------------
// K3b: right-looking MFMA solve, all global loads PREFETCHED off the barrier
// chain (Minv, V, invs, and phase-3 A fragments; statically unrolled with
// wave-uniform predication). U stride 1031 (odd) spreads banks.
// ---------------------------------------------------------------------------
__global__ __launch_bounds__(1024) void solve_mfma_kernel(
    const u16* __restrict__ A, const float* __restrict__ invs,
    const float* __restrict__ Vt, float* __restrict__ Yout) {
  const int sys = blockIdx.x, cq = blockIdx.y;
  const int bb = sys >> 3, kvh = (sys & 7) >> 1;
  const int c0 = cq * 16;
  const int tid = threadIdx.x;
  const int lane = tid & 63, w = tid >> 6;  // 16 waves
  const int ln = lane & 15, kg = lane >> 4;

  const u16* Ab = A + ((size_t)sys << 20);
  const float* Vb = Vt + ((size_t)(bb * KVHN + kvh) * TT) * 64;
  float* Yg = Yout + (size_t)sys * TT * 64;

  __shared__ float U[16][1031];
  __shared__ u16 yh[16 * 64], yl[16 * 64];
  __shared__ u16 uh[16 * 64], ul[16 * 64];

  {
    float* Uf = &U[0][0];
    for (int i = tid; i < 16 * 1031; i += 1024) Uf[i] = 0.f;
  }
  __syncthreads();

  for (int k = 0; k < 16; ++k) {
    const int rg0 = k * 64;

    // ---- prefetch: every global load this step needs, no LDS deps ----
    uint4 pm0 = {}, pm1 = {};
    f32x4 pv = {0.f, 0.f, 0.f, 0.f}, psi = {0.f, 0.f, 0.f, 0.f};
    if (w < 4) {
      const u16* mrow = Ab + (size_t)(rg0 + w * 16 + ln) * 1024 + rg0;
      pm0 = *reinterpret_cast<const uint4*>(mrow + kg * 8);
      pm1 = *reinterpret_cast<const uint4*>(mrow + 32 + kg * 8);
#pragma unroll
      for (int j = 0; j < 4; ++j) {
        int gr = rg0 + w * 16 + kg * 4 + j;
        pv[j] = Vb[(size_t)gr * 64 + c0 + ln];
        psi[j] = invs[sys * 1024 + gr];
      }
    }
    const int nu = (15 - k) * 4;
    uint4 pa0[4], pa1[4];
    bool val[4];
#pragma unroll
    for (int t = 0; t < 4; ++t) {
      int un = w + 16 * t;
      val[t] = un < nu;
      if (val[t]) {
        const u16* ar =
            Ab + (size_t)((k + 1 + (un >> 2)) * 64 + (un & 3) * 16 + ln) * 1024 +
            rg0;
        pa0[t] = *reinterpret_cast<const uint4*>(ar + kg * 8);
        pa1[t] = *reinterpret_cast<const uint4*>(ar + 32 + kg * 8);
      }
    }

    // ---- phase 1 (waves 0-3): u = V - s*U ----
    if (w < 4) {
      f32x4 u;
#pragma unroll
      for (int j = 0; j < 4; ++j) {
        int gr = rg0 + w * 16 + kg * 4 + j;
        u[j] = pv[j] - psi[j] * U[ln][gr];
      }
      st_split_lds(uh, ul, ln, w * 16 + kg * 4, u);
    }
    __syncthreads();

    // ---- phase 2 (waves 0-3): y = Minv @ (uh + ul) ----
    if (w < 4) {
      bf16x8 ma0 = __builtin_bit_cast(bf16x8, pm0);
      bf16x8 ma1 = __builtin_bit_cast(bf16x8, pm1);
      f32x4 y = {0.f, 0.f, 0.f, 0.f};
      y = MFMA(ma0, ld8_lds(uh, ln, kg), y);
      y = MFMA(ma1, ld8_lds(uh, ln, 4 + kg), y);
      y = MFMA(ma0, ld8_lds(ul, ln, kg), y);
      y = MFMA(ma1, ld8_lds(ul, ln, 4 + kg), y);
#pragma unroll
      for (int j = 0; j < 4; ++j)
        Yg[(size_t)(rg0 + w * 16 + kg * 4 + j) * 64 + c0 + ln] = y[j];
      st_split_lds(yh, yl, ln, w * 16 + kg * 4, y);
    }
    __syncthreads();

    // ---- phase 3 (all waves): U[i] += A(i,k) * y_k, from prefetched regs ----
#pragma unroll
    for (int t = 0; t < 4; ++t) {
      if (val[t]) {
        int un = w + 16 * t;
        int rb = (k + 1 + (un >> 2)) * 64 + (un & 3) * 16 + kg * 4;
        bf16x8 a0 = __builtin_bit_cast(bf16x8, pa0[t]);
        bf16x8 a1 = __builtin_bit_cast(bf16x8, pa1[t]);
        f32x4 s = {0.f, 0.f, 0.f, 0.f};
        s = MFMA(a0, ld8_lds(yh, ln, kg), s);
        s = MFMA(a1, ld8_lds(yh, ln, 4 + kg), s);
        s = MFMA(a0, ld8_lds(yl, ln, kg), s);
        s = MFMA(a1, ld8_lds(yl, ln, 4 + kg), s);
#pragma unroll
        for (int j = 0; j < 4; ++j) U[ln][rb + j] += s[j];
      }
    }
    __syncthreads();
  }
}

// ---------------------------------------------------------------------------
// K4: out = x + Y2d @ Wo via MFMA (hi/lo). (unchanged r13)
// ---------------------------------------------------------------------------
__global__ __launch_bounds__(256) void out_proj_mfma_kernel(
    const float* __restrict__ Y, const u16* __restrict__ WotH,
    const u16* __restrict__ WotL, const float* __restrict__ x,
    float* __restrict__ out) {
  const int bx = blockIdx.x, by = blockIdx.y;
  const int tid = threadIdx.x;
  const int lane = tid & 63, w = tid >> 6;
  const int ln = lane & 15, kg = lane >> 4;
  const int n0 = by * 64;
  const int m = bx * 64 + w * 16 + ln;
  const int b = m >> 10, t = m & 1023;

  const u16* wh0 = WotH + (size_t)(n0 + ln) * 512 + kg * 8;
  const u16* wl0 = WotL + (size_t)(n0 + ln) * 512 + kg * 8;

  f32x4 acc[4];
#pragma unroll
  for (int ct = 0; ct < 4; ++ct) acc[ct] = {0.f, 0.f, 0.f, 0.f};

  for (int kk = 0; kk < 16; ++kk) {
    const int k0 = kk * 32;
    const int h = k0 >> 6, d0 = (k0 & 63) + kg * 8;
    bf16x8 ah, al;
    cvt8(Y + ((size_t)(b * HH + h) * TT + t) * 64 + d0, ah, al);
#pragma unroll
    for (int ct = 0; ct < 4; ++ct) {
      bf16x8 bh = ld8_g(wh0 + (size_t)(ct * 16) * 512 + k0);
      bf16x8 bl = ld8_g(wl0 + (size_t)(ct * 16) * 512 + k0);
      acc[ct] = MFMA(ah, bh, acc[ct]);
      acc[ct] = MFMA(al, bh, acc[ct]);
      acc[ct] = MFMA(ah, bl, acc[ct]);
    }
  }

#pragma unroll
  for (int ct = 0; ct < 4; ++ct) {
#pragma unroll
    for (int j = 0; j < 4; ++j) {
      size_t row = (size_t)(bx * 64 + w * 16 + kg * 4 + j);
      int col = n0 + ct * 16 + ln;
      out[row * 512 + col] = x[row * 512 + col] + acc[ct][j];
    }
  }
}

// ---------------------------------------------------------------------------
extern "C" void kernel_launch(void* const* d_in, const int* in_sizes, int n_in,
                              void* d_out, int out_size, void* d_ws,
                              size_t ws_size, hipStream_t stream) {
  (void)in_sizes; (void)n_in; (void)out_size; (void)ws_size;
  const float* x = (const float*)d_in[0];
  const float* cosb = (const float*)d_in[1];
  const float* sinb = (const float*)d_in[2];
  const float* Wq = (const float*)d_in[3];
  const float* Wk = (const float*)d_in[4];
  const float* Wv = (const float*)d_in[5];
  const float* Wo = (const float*)d_in[6];
  float* out = (float*)d_out;

  float* ws = (float*)d_ws;
  float* Q = ws;                        // 1,048,576 f
  float* Kt = Q + (size_t)1048576;      //   524,288 f
  float* Vt = Kt + (size_t)524288;      //   524,288 f
  float* Yb = Vt + (size_t)524288;      // 1,048,576 f
  float* invs = Yb + (size_t)1048576;   //    16,384 f
  float* part = invs + (size_t)16384;   //   262,144 f
  u16* A = (u16*)(part + 262144);       // 16,777,216 u16 = 32 MB
  u16* WtH = A + (size_t)16777216;      //   524,288 u16
  u16* WtL = WtH + (size_t)524288;
  u16* WotH = WtL + (size_t)524288;     //   262,144 u16
  u16* WotL = WotH + (size_t)262144;
  u16* Xh = WotL + (size_t)262144;      // 1,048,576 u16
  u16* Xl = Xh + (size_t)1048576;       // total ~55 MB

  prep_kernel<<<dim3(8, 56), 256, 0, stream>>>(x, Wq, Wk, Wv, Wo, WtH, WtL,
                                               WotH, WotL, Xh, Xl);
  qkv_mfma_kernel<<<dim3(32, 16), 256, 0, stream>>>(Xh, Xl, WtH, WtL, cosb,
                                                    sinb, Q, Kt, Vt);
  logits_mfma_kernel<<<dim3(136, 16), 256, 0, stream>>>(Q, Kt, A, part);
  diaginv_kernel<<<dim3(16, 16), 256, 0, stream>>>(A, part, invs);
  solve_mfma_kernel<<<dim3(16, 4), 1024, 0, stream>>>(A, invs, Vt, Yb);
  out_proj_mfma_kernel<<<dim3(32, 8), 256, 0, stream>>>(Yb, WotH, WotL, x, out);
}

// Round 15
// 168.112 us; speedup vs baseline: 2.2268x; 1.1916x over previous
//
#include <hip/hip_runtime.h>
#include <cmath>

#define TT 1024
#define HH 8
#define KVHN 4

typedef unsigned short u16;
typedef __attribute__((ext_vector_type(8))) short bf16x8;
typedef __attribute__((ext_vector_type(4))) float f32x4;

#define MFMA(a, b, c) __builtin_amdgcn_mfma_f32_16x16x32_bf16(a, b, c, 0, 0, 0)

__device__ __forceinline__ float bflo(unsigned u) { return __uint_as_float(u << 16); }
__device__ __forceinline__ float bfhi(unsigned u) { return __uint_as_float(u & 0xffff0000u); }
__device__ __forceinline__ u16 bfr(float f) {
  unsigned u = __float_as_uint(f);
  return (u16)((u + 0x7fffu + ((u >> 16) & 1u)) >> 16);
}

__device__ __forceinline__ bf16x8 ld8_g(const u16* __restrict__ p) {
  uint4 v = *reinterpret_cast<const uint4*>(p);
  return __builtin_bit_cast(bf16x8, v);
}
__device__ __forceinline__ bf16x8 ld8_lds(const u16* s, int col, int k8) {
  const uint4* p = reinterpret_cast<const uint4*>(s);
  return __builtin_bit_cast(bf16x8, p[col * 8 + (k8 ^ (col & 7))]);
}
__device__ __forceinline__ void st_split_lds(u16* sh, u16* sl, int col, int r0,
                                             f32x4 v) {
  u16 hh[4], ll[4];
#pragma unroll
  for (int j = 0; j < 4; ++j) {
    u16 hb = bfr(v[j]);
    hh[j] = hb;
    ll[j] = bfr(v[j] - __uint_as_float((unsigned)hb << 16));
  }
  uint2 ph, pl;
  ph.x = (unsigned)hh[0] | ((unsigned)hh[1] << 16);
  ph.y = (unsigned)hh[2] | ((unsigned)hh[3] << 16);
  pl.x = (unsigned)ll[0] | ((unsigned)ll[1] << 16);
  pl.y = (unsigned)ll[2] | ((unsigned)ll[3] << 16);
  int idx = col * 64 + (((r0 >> 3) ^ (col & 7)) << 3) + (r0 & 7);
  *reinterpret_cast<uint2*>(sh + idx) = ph;
  *reinterpret_cast<uint2*>(sl + idx) = pl;
}
// load 8 consecutive f32 at p, split into hi/lo bf16x8 fragments
__device__ __forceinline__ void cvt8(const float* __restrict__ p, bf16x8& h,
                                     bf16x8& l) {
  float4 a = *reinterpret_cast<const float4*>(p);
  float4 b = *reinterpret_cast<const float4*>(p + 4);
  float v[8] = {a.x, a.y, a.z, a.w, b.x, b.y, b.z, b.w};
  unsigned hh[8], ll[8];
#pragma unroll
  for (int j = 0; j < 8; ++j) {
    u16 hb = bfr(v[j]);
    hh[j] = hb;
    ll[j] = bfr(v[j] - __uint_as_float((unsigned)hb << 16));
  }
  uint4 H, L;
  H.x = hh[0] | (hh[1] << 16); H.y = hh[2] | (hh[3] << 16);
  H.z = hh[4] | (hh[5] << 16); H.w = hh[6] | (hh[7] << 16);
  L.x = ll[0] | (ll[1] << 16); L.y = ll[2] | (ll[3] << 16);
  L.z = ll[4] | (ll[5] << 16); L.w = ll[6] | (ll[7] << 16);
  h = __builtin_bit_cast(bf16x8, H);
  l = __builtin_bit_cast(bf16x8, L);
}

// ---------------------------------------------------------------------------
// K0: prep — transpose+split weights to bf16 hi/lo [n][k]; convert x to hi/lo.
// (unchanged, proven round 13)
// ---------------------------------------------------------------------------
__global__ __launch_bounds__(256) void prep_kernel(
    const float* __restrict__ x, const float* __restrict__ Wq,
    const float* __restrict__ Wk, const float* __restrict__ Wv,
    const float* __restrict__ Wo, u16* __restrict__ WtH, u16* __restrict__ WtL,
    u16* __restrict__ WotH, u16* __restrict__ WotL, u16* __restrict__ Xh,
    u16* __restrict__ Xl) {
  const int kt = blockIdx.x, nt = blockIdx.y;
  const int tid = threadIdx.x;
  const int k0 = kt * 64;

  if (nt >= 24) {
    const int r0 = (nt - 24) * 64;
    const int rr = tid >> 2, kc0 = (tid & 3) * 16;
    const float* src = x + (size_t)(r0 + rr) * 512 + k0 + kc0;
    u16* dh = Xh + (size_t)(r0 + rr) * 512 + k0 + kc0;
    u16* dl = Xl + (size_t)(r0 + rr) * 512 + k0 + kc0;
#pragma unroll
    for (int m = 0; m < 4; ++m) {
      float4 v = *reinterpret_cast<const float4*>(src + m * 4);
      float vv[4] = {v.x, v.y, v.z, v.w};
      u16 hh[4], ll[4];
#pragma unroll
      for (int j = 0; j < 4; ++j) {
        u16 hb = bfr(vv[j]);
        hh[j] = hb;
        ll[j] = bfr(vv[j] - __uint_as_float((unsigned)hb << 16));
      }
      uint2 ph, pl;
      ph.x = (unsigned)hh[0] | ((unsigned)hh[1] << 16);
      ph.y = (unsigned)hh[2] | ((unsigned)hh[3] << 16);
      pl.x = (unsigned)ll[0] | ((unsigned)ll[1] << 16);
      pl.y = (unsigned)ll[2] | ((unsigned)ll[3] << 16);
      *reinterpret_cast<uint2*>(dh + m * 4) = ph;
      *reinterpret_cast<uint2*>(dl + m * 4) = pl;
    }
    return;
  }

  const float* Wsel;
  int wstride, wc0;
  u16 *oh, *ol;
  if (nt < 16) {
    if (nt < 8) { Wsel = Wq; wstride = 512; wc0 = nt * 64; }
    else if (nt < 12) { Wsel = Wk; wstride = 256; wc0 = (nt - 8) * 64; }
    else { Wsel = Wv; wstride = 256; wc0 = (nt - 12) * 64; }
    oh = WtH + (size_t)(nt * 64) * 512;
    ol = WtL + (size_t)(nt * 64) * 512;
  } else {
    Wsel = Wo; wstride = 512; wc0 = (nt - 16) * 64;
    oh = WotH + (size_t)((nt - 16) * 64) * 512;
    ol = WotL + (size_t)((nt - 16) * 64) * 512;
  }

  __shared__ float Ws[64][68];
#pragma unroll
  for (int m = 0; m < 4; ++m) {
    int f = m * 256 + tid;
    int rr = f >> 4, dc = (f & 15) * 4;
    *reinterpret_cast<float4*>(&Ws[rr][dc]) =
        *reinterpret_cast<const float4*>(Wsel + (size_t)(k0 + rr) * wstride + wc0 + dc);
  }
  __syncthreads();

  const int nr = tid >> 2, kc0 = (tid & 3) * 16;
  u16* dh = oh + (size_t)nr * 512 + k0 + kc0;
  u16* dl = ol + (size_t)nr * 512 + k0 + kc0;
#pragma unroll
  for (int i = 0; i < 16; i += 2) {
    float a = Ws[kc0 + i][nr], b = Ws[kc0 + i + 1][nr];
    u16 ha = bfr(a), hb2 = bfr(b);
    u16 la = bfr(a - __uint_as_float((unsigned)ha << 16));
    u16 lb = bfr(b - __uint_as_float((unsigned)hb2 << 16));
    *reinterpret_cast<unsigned*>(dh + i) = (unsigned)ha | ((unsigned)hb2 << 16);
    *reinterpret_cast<unsigned*>(dl + i) = (unsigned)la | ((unsigned)lb << 16);
  }
}

// ---------------------------------------------------------------------------
// K1: QKV projection via MFMA (hi/lo split) + fused RoPE. (unchanged r13)
// ---------------------------------------------------------------------------
__global__ __launch_bounds__(256) void qkv_mfma_kernel(
    const u16* __restrict__ Xh, const u16* __restrict__ Xl,
    const u16* __restrict__ WtH, const u16* __restrict__ WtL,
    const float* __restrict__ cosb, const float* __restrict__ sinb,
    float* __restrict__ Q, float* __restrict__ Kt, float* __restrict__ Vt) {
  const int bx = blockIdx.x, cy = blockIdx.y;
  const int tid = threadIdx.x;
  const int lane = tid & 63, w = tid >> 6;
  const int ln = lane & 15, kg = lane >> 4;
  const int n0 = cy * 64;

  const u16* xh = Xh + (size_t)(bx * 64 + w * 16 + ln) * 512 + kg * 8;
  const u16* xl = Xl + (size_t)(bx * 64 + w * 16 + ln) * 512 + kg * 8;
  const u16* wh0 = WtH + (size_t)(n0 + ln) * 512 + kg * 8;
  const u16* wl0 = WtL + (size_t)(n0 + ln) * 512 + kg * 8;

  f32x4 acc[4];
#pragma unroll
  for (int ct = 0; ct < 4; ++ct) acc[ct] = {0.f, 0.f, 0.f, 0.f};

  for (int kk = 0; kk < 16; ++kk) {
    const int k0 = kk * 32;
    bf16x8 ah = ld8_g(xh + k0);
    bf16x8 al = ld8_g(xl + k0);
#pragma unroll
    for (int ct = 0; ct < 4; ++ct) {
      bf16x8 bh = ld8_g(wh0 + (size_t)(ct * 16) * 512 + k0);
      bf16x8 bl = ld8_g(wl0 + (size_t)(ct * 16) * 512 + k0);
      acc[ct] = MFMA(ah, bh, acc[ct]);
      acc[ct] = MFMA(al, bh, acc[ct]);
      acc[ct] = MFMA(ah, bl, acc[ct]);
    }
  }

  __shared__ float Xs[64][68];
#pragma unroll
  for (int ct = 0; ct < 4; ++ct)
#pragma unroll
    for (int j = 0; j < 4; ++j) Xs[w * 16 + kg * 4 + j][ct * 16 + ln] = acc[ct][j];
  __syncthreads();

#pragma unroll
  for (int m = 0; m < 16; ++m) {
    int f = m * 256 + tid;
    int rr = f >> 6, d = f & 63;
    int row = bx * 64 + rr, b = row >> 10, t = row & 1023;
    float val;
    if (cy < 12) {
      int dd = d & 31;
      float c = cosb[t * 32 + dd], s = sinb[t * 32 + dd];
      float v1 = Xs[rr][dd], v2 = Xs[rr][dd + 32];
      val = (d < 32) ? (v1 * c + v2 * s) : (v2 * c - v1 * s);
    } else {
      val = Xs[rr][d];
    }
    if (cy < 8)
      Q[((size_t)(b * HH + cy) * TT + t) * 64 + d] = val;
    else if (cy < 12)
      Kt[((size_t)(b * KVHN + cy - 8) * TT + t) * 64 + d] = val;
    else
      Vt[((size_t)(b * KVHN + cy - 12) * TT + t) * 64 + d] = val;
  }
}

// ---------------------------------------------------------------------------
// K2: MFMA causal logits + exp (UNNORMALIZED) -> A (bf16). (unchanged r12)
// ---------------------------------------------------------------------------
__global__ __launch_bounds__(256) void logits_mfma_kernel(
    const float* __restrict__ Q, const float* __restrict__ Kt,
    u16* __restrict__ A, float* __restrict__ part) {
  const int n = blockIdx.x, sys = blockIdx.y;
  int it = 0;
  while ((it + 1) * (it + 2) / 2 <= n) ++it;
  const int jt = n - it * (it + 1) / 2;
  const int b = sys >> 3, kvh = (sys & 7) >> 1;
  const int tid = threadIdx.x;
  const int lane = tid & 63, w = tid >> 6;
  const int ln = lane & 15, kg = lane >> 4;
  const int m0 = w * 16;

  const float* Qr = Q + ((size_t)sys * TT + it * 64 + m0 + ln) * 64;
  const float* Kb = Kt + ((size_t)(b * KVHN + kvh) * TT + jt * 64) * 64;
  u16* Aout = A + ((size_t)sys << 20);

  bf16x8 qh0, ql0, qh1, ql1;
  cvt8(Qr + kg * 8, qh0, ql0);
  cvt8(Qr + 32 + kg * 8, qh1, ql1);

  f32x4 acc[4];
#pragma unroll
  for (int ct = 0; ct < 4; ++ct) {
    const float* Kr = Kb + (size_t)(ct * 16 + ln) * 64;
    bf16x8 kh0, kl0, kh1, kl1;
    cvt8(Kr + kg * 8, kh0, kl0);
    cvt8(Kr + 32 + kg * 8, kh1, kl1);
    f32x4 a = {0.f, 0.f, 0.f, 0.f};
    a = MFMA(qh0, kh0, a);
    a = MFMA(qh1, kh1, a);
    a = MFMA(qh0, kl0, a);
    a = MFMA(qh1, kl1, a);
    a = MFMA(ql0, kh0, a);
    a = MFMA(ql1, kh1, a);
    acc[ct] = a;
  }

  const int grow0 = it * 64 + m0;
  const bool full = (jt < it);
  float s[4] = {0.f, 0.f, 0.f, 0.f};
#pragma unroll
  for (int ct = 0; ct < 4; ++ct) {
    int col = jt * 64 + ct * 16 + ln;
#pragma unroll
    for (int j = 0; j < 4; ++j) {
      int row = grow0 + kg * 4 + j;
      float e = (full || col <= row) ? __expf(acc[ct][j] * 0.125f) : 0.f;
      s[j] += e;
      Aout[(size_t)row * 1024 + col] = bfr(e);
    }
  }

#pragma unroll
  for (int off = 1; off < 16; off <<= 1) {
#pragma unroll
    for (int j = 0; j < 4; ++j) s[j] += __shfl_xor(s[j], off);
  }
  if (ln == 0) {
#pragma unroll
    for (int j = 0; j < 4; ++j)
      part[((size_t)(sys * 16 + jt)) * 1024 + grow0 + kg * 4 + j] = s[j];
  }
}

// ---------------------------------------------------------------------------
// K3a: diag-block inversion, BARRIER-FREE. One wave per (k, sys); lane c
// solves column c of (I + S*L_kk) w = e_c with all state in registers
// (fully unrolled, static indexing). Scaled matrix stored TRANSPOSED in LDS
// so the rank-1 update reads are float4 broadcasts. Also computes invs.
// ---------------------------------------------------------------------------
__global__ __launch_bounds__(64) void diaginv_kernel(
    u16* __restrict__ A, const float* __restrict__ part,
    float* __restrict__ invs) {
  const int k = blockIdx.x, sys = blockIdx.y;
  const int c = threadIdx.x;  // lane = column (and row in prep phase)

  u16* Ab = A + ((size_t)sys << 20) + (size_t)(k * 64) * 1024 + k * 64;

  __shared__ float MsT[64][68];  // MsT[j][i] = M[i][j] = sv[i]*L[i][j]
  __shared__ float dv[64];       // 1 / M[r][r]

  // prep: thread r loads row r, computes sv[r], writes transposed scaled row
  {
    const int r = c;
    float row[64];
#pragma unroll
    for (int m8 = 0; m8 < 8; ++m8) {
      uint4 v = *reinterpret_cast<const uint4*>(Ab + (size_t)r * 1024 + m8 * 8);
      row[m8 * 8 + 0] = bflo(v.x); row[m8 * 8 + 1] = bfhi(v.x);
      row[m8 * 8 + 2] = bflo(v.y); row[m8 * 8 + 3] = bfhi(v.y);
      row[m8 * 8 + 4] = bflo(v.z); row[m8 * 8 + 5] = bfhi(v.z);
      row[m8 * 8 + 6] = bflo(v.w); row[m8 * 8 + 7] = bfhi(v.w);
    }
    float s = 0.f;
    for (int jt = 0; jt <= k; ++jt)
      s += part[((size_t)(sys * 16 + jt)) * 1024 + k * 64 + r];
    float svr = 1.0f / s;
    invs[sys * 1024 + k * 64 + r] = svr;
    dv[r] = 1.0f / (1.0f + svr * row[r]);
#pragma unroll
    for (int j = 0; j < 64; ++j) MsT[j][r] = svr * row[j];
  }
  __syncthreads();

  // preload diagonal inverses into registers (broadcast reads, off-chain)
  float dvr[64];
#pragma unroll
  for (int q = 0; q < 64; ++q) dvr[q] = dv[q];

  float w[64], acc[64];
#pragma unroll
  for (int r = 0; r < 64; ++r) acc[r] = 0.f;

#pragma unroll
  for (int r = 0; r < 64; ++r) {
    float wr = ((r == c) ? 1.0f : 0.0f) - acc[r];
    wr *= dvr[r];
    w[r] = wr;
    // update acc[i] += M[i][r]*wr for i>r (float4 broadcast reads; updates
    // to already-consumed acc[i<=r] inside the first chunk are dead/harmless)
#pragma unroll
    for (int q = (r + 1) >> 2; q < 16; ++q) {
      float4 m4 = *reinterpret_cast<const float4*>(&MsT[r][q * 4]);
      acc[q * 4 + 0] += m4.x * wr;
      acc[q * 4 + 1] += m4.y * wr;
      acc[q * 4 + 2] += m4.z * wr;
      acc[q * 4 + 3] += m4.w * wr;
    }
  }

  // writeback: lane c stores column c as bf16 (coalesced across lanes per row)
#pragma unroll
  for (int r = 0; r < 64; ++r) Ab[(size_t)r * 1024 + c] = bfr(w[r]);
}

// ---------------------------------------------------------------------------
// K3b: right-looking MFMA solve with prefetched globals. (unchanged r14)
// ---------------------------------------------------------------------------
__global__ __launch_bounds__(1024) void solve_mfma_kernel(
    const u16* __restrict__ A, const float* __restrict__ invs,
    const float* __restrict__ Vt, float* __restrict__ Yout) {
  const int sys = blockIdx.x, cq = blockIdx.y;
  const int bb = sys >> 3, kvh = (sys & 7) >> 1;
  const int c0 = cq * 16;
  const int tid = threadIdx.x;
  const int lane = tid & 63, w = tid >> 6;
  const int ln = lane & 15, kg = lane >> 4;

  const u16* Ab = A + ((size_t)sys << 20);
  const float* Vb = Vt + ((size_t)(bb * KVHN + kvh) * TT) * 64;
  float* Yg = Yout + (size_t)sys * TT * 64;

  __shared__ float U[16][1031];
  __shared__ u16 yh[16 * 64], yl[16 * 64];
  __shared__ u16 uh[16 * 64], ul[16 * 64];

  {
    float* Uf = &U[0][0];
    for (int i = tid; i < 16 * 1031; i += 1024) Uf[i] = 0.f;
  }
  __syncthreads();

  for (int k = 0; k < 16; ++k) {
    const int rg0 = k * 64;

    uint4 pm0 = {}, pm1 = {};
    f32x4 pv = {0.f, 0.f, 0.f, 0.f}, psi = {0.f, 0.f, 0.f, 0.f};
    if (w < 4) {
      const u16* mrow = Ab + (size_t)(rg0 + w * 16 + ln) * 1024 + rg0;
      pm0 = *reinterpret_cast<const uint4*>(mrow + kg * 8);
      pm1 = *reinterpret_cast<const uint4*>(mrow + 32 + kg * 8);
#pragma unroll
      for (int j = 0; j < 4; ++j) {
        int gr = rg0 + w * 16 + kg * 4 + j;
        pv[j] = Vb[(size_t)gr * 64 + c0 + ln];
        psi[j] = invs[sys * 1024 + gr];
      }
    }
    const int nu = (15 - k) * 4;
    uint4 pa0[4], pa1[4];
    bool val[4];
#pragma unroll
    for (int t = 0; t < 4; ++t) {
      int un = w + 16 * t;
      val[t] = un < nu;
      if (val[t]) {
        const u16* ar =
            Ab + (size_t)((k + 1 + (un >> 2)) * 64 + (un & 3) * 16 + ln) * 1024 +
            rg0;
        pa0[t] = *reinterpret_cast<const uint4*>(ar + kg * 8);
        pa1[t] = *reinterpret_cast<const uint4*>(ar + 32 + kg * 8);
      }
    }

    if (w < 4) {
      f32x4 u;
#pragma unroll
      for (int j = 0; j < 4; ++j) {
        int gr = rg0 + w * 16 + kg * 4 + j;
        u[j] = pv[j] - psi[j] * U[ln][gr];
      }
      st_split_lds(uh, ul, ln, w * 16 + kg * 4, u);
    }
    __syncthreads();

    if (w < 4) {
      bf16x8 ma0 = __builtin_bit_cast(bf16x8, pm0);
      bf16x8 ma1 = __builtin_bit_cast(bf16x8, pm1);
      f32x4 y = {0.f, 0.f, 0.f, 0.f};
      y = MFMA(ma0, ld8_lds(uh, ln, kg), y);
      y = MFMA(ma1, ld8_lds(uh, ln, 4 + kg), y);
      y = MFMA(ma0, ld8_lds(ul, ln, kg), y);
      y = MFMA(ma1, ld8_lds(ul, ln, 4 + kg), y);
#pragma unroll
      for (int j = 0; j < 4; ++j)
        Yg[(size_t)(rg0 + w * 16 + kg * 4 + j) * 64 + c0 + ln] = y[j];
      st_split_lds(yh, yl, ln, w * 16 + kg * 4, y);
    }
    __syncthreads();

#pragma unroll
    for (int t = 0; t < 4; ++t) {
      if (val[t]) {
        int un = w + 16 * t;
        int rb = (k + 1 + (un >> 2)) * 64 + (un & 3) * 16 + kg * 4;
        bf16x8 a0 = __builtin_bit_cast(bf16x8, pa0[t]);
        bf16x8 a1 = __builtin_bit_cast(bf16x8, pa1[t]);
        f32x4 s = {0.f, 0.f, 0.f, 0.f};
        s = MFMA(a0, ld8_lds(yh, ln, kg), s);
        s = MFMA(a1, ld8_lds(yh, ln, 4 + kg), s);
        s = MFMA(a0, ld8_lds(yl, ln, kg), s);
        s = MFMA(a1, ld8_lds(yl, ln, 4 + kg), s);
#pragma unroll
        for (int j = 0; j < 4; ++j) U[ln][rb + j] += s[j];
      }
    }
    __syncthreads();
  }
}

// ---------------------------------------------------------------------------
// K4: out = x + Y2d @ Wo via MFMA (hi/lo). (unchanged r13)
// ---------------------------------------------------------------------------
__global__ __launch_bounds__(256) void out_proj_mfma_kernel(
    const float* __restrict__ Y, const u16* __restrict__ WotH,
    const u16* __restrict__ WotL, const float* __restrict__ x,
    float* __restrict__ out) {
  const int bx = blockIdx.x, by = blockIdx.y;
  const int tid = threadIdx.x;
  const int lane = tid & 63, w = tid >> 6;
  const int ln = lane & 15, kg = lane >> 4;
  const int n0 = by * 64;
  const int m = bx * 64 + w * 16 + ln;
  const int b = m >> 10, t = m & 1023;

  const u16* wh0 = WotH + (size_t)(n0 + ln) * 512 + kg * 8;
  const u16* wl0 = WotL + (size_t)(n0 + ln) * 512 + kg * 8;

  f32x4 acc[4];
#pragma unroll
  for (int ct = 0; ct < 4; ++ct) acc[ct] = {0.f, 0.f, 0.f, 0.f};

  for (int kk = 0; kk < 16; ++kk) {
    const int k0 = kk * 32;
    const int h = k0 >> 6, d0 = (k0 & 63) + kg * 8;
    bf16x8 ah, al;
    cvt8(Y + ((size_t)(b * HH + h) * TT + t) * 64 + d0, ah, al);
#pragma unroll
    for (int ct = 0; ct < 4; ++ct) {
      bf16x8 bh = ld8_g(wh0 + (size_t)(ct * 16) * 512 + k0);
      bf16x8 bl = ld8_g(wl0 + (size_t)(ct * 16) * 512 + k0);
      acc[ct] = MFMA(ah, bh, acc[ct]);
      acc[ct] = MFMA(al, bh, acc[ct]);
      acc[ct] = MFMA(ah, bl, acc[ct]);
    }
  }

#pragma unroll
  for (int ct = 0; ct < 4; ++ct) {
#pragma unroll
    for (int j = 0; j < 4; ++j) {
      size_t row = (size_t)(bx * 64 + w * 16 + kg * 4 + j);
      int col = n0 + ct * 16 + ln;
      out[row * 512 + col] = x[row * 512 + col] + acc[ct][j];
    }
  }
}

// ---------------------------------------------------------------------------
extern "C" void kernel_launch(void* const* d_in, const int* in_sizes, int n_in,
                              void* d_out, int out_size, void* d_ws,
                              size_t ws_size, hipStream_t stream) {
  (void)in_sizes; (void)n_in; (void)out_size; (void)ws_size;
  const float* x = (const float*)d_in[0];
  const float* cosb = (const float*)d_in[1];
  const float* sinb = (const float*)d_in[2];
  const float* Wq = (const float*)d_in[3];
  const float* Wk = (const float*)d_in[4];
  const float* Wv = (const float*)d_in[5];
  const float* Wo = (const float*)d_in[6];
  float* out = (float*)d_out;

  float* ws = (float*)d_ws;
  float* Q = ws;                        // 1,048,576 f
  float* Kt = Q + (size_t)1048576;      //   524,288 f
  float* Vt = Kt + (size_t)524288;      //   524,288 f
  float* Yb = Vt + (size_t)524288;      // 1,048,576 f
  float* invs = Yb + (size_t)1048576;   //    16,384 f
  float* part = invs + (size_t)16384;   //   262,144 f
  u16* A = (u16*)(part + 262144);       // 16,777,216 u16 = 32 MB
  u16* WtH = A + (size_t)16777216;      //   524,288 u16
  u16* WtL = WtH + (size_t)524288;
  u16* WotH = WtL + (size_t)524288;     //   262,144 u16
  u16* WotL = WotH + (size_t)262144;
  u16* Xh = WotL + (size_t)262144;      // 1,048,576 u16
  u16* Xl = Xh + (size_t)1048576;       // total ~55 MB

  prep_kernel<<<dim3(8, 56), 256, 0, stream>>>(x, Wq, Wk, Wv, Wo, WtH, WtL,
                                               WotH, WotL, Xh, Xl);
  qkv_mfma_kernel<<<dim3(32, 16), 256, 0, stream>>>(Xh, Xl, WtH, WtL, cosb,
                                                    sinb, Q, Kt, Vt);
  logits_mfma_kernel<<<dim3(136, 16), 256, 0, stream>>>(Q, Kt, A, part);
  diaginv_kernel<<<dim3(16, 16), 64, 0, stream>>>(A, part, invs);
  solve_mfma_kernel<<<dim3(16, 4), 1024, 0, stream>>>(A, invs, Vt, Yb);
  out_proj_mfma_kernel<<<dim3(32, 8), 256, 0, stream>>>(Yb, WotH, WotL, x, out);
}